// Round 5
// baseline (413.396 us; speedup 1.0000x reference)
//
#include <hip/hip_runtime.h>

// ---------------- problem constants ----------------
#define ICn 128
#define OCn 256
#define ISn 48      // x spatial
#define OSn 24      // out spatial
#define YV  117649  // 49^3
#define K0f (1.0f/11.0f)
#define K1f (3.0f/11.0f)

typedef short  short8  __attribute__((ext_vector_type(8)));
typedef float  floatx4 __attribute__((ext_vector_type(4)));

static __device__ __forceinline__ unsigned short f2bf(float f) {
    union { float f; unsigned u; } v; v.f = f;
    unsigned r = (v.u + 0x7FFF + ((v.u >> 16) & 1)) >> 16;   // RNE
    return (unsigned short)r;
}

// async 16B global -> LDS (dest = wave-uniform base + lane*16)
static __device__ __forceinline__ void async_copy16(
    unsigned short* lds_base, const unsigned short* gsrc) {
    __builtin_amdgcn_global_load_lds(
        (const __attribute__((address_space(1))) void*)gsrc,
        (__attribute__((address_space(3))) void*)lds_base, 16, 0, 0);
}

// ============================================================
// Kernel 0: repack w (fp32, [256][128][3][3][3]) -> bf16 wt
// wt layout: [g=2][tap=27][ch=4][oc=128][ic=32]
// ============================================================
__global__ __launch_bounds__(256) void w_pack(
    const float* __restrict__ w, unsigned short* __restrict__ wt)
{
    __shared__ unsigned short lw[27648];   // [ol=8][ic=128][t=27] bf16
    const int tid = threadIdx.x;
    const int b = blockIdx.x;              // 0..31
    const float* src = w + (size_t)b * 27648;
    for (int i4 = tid; i4 < 6912; i4 += 256) {
        floatx4 v = *(const floatx4*)(src + (size_t)i4*4);
        ushort4 u;
        u.x = f2bf(v.x); u.y = f2bf(v.y); u.z = f2bf(v.z); u.w = f2bf(v.w);
        *(ushort4*)(&lw[i4*4]) = u;
    }
    __syncthreads();
    const int g = b >> 4, bo = b & 15;
    for (int idx = tid; idx < 27648; idx += 256) {
        int i  = idx & 31;
        int ol = (idx >> 5) & 7;
        int rest = idx >> 8;               // t*4 + ch
        int ch = rest & 3, t = rest >> 2;
        unsigned short v = lw[(ol*128 + ch*32 + i)*27 + t];
        wt[(((size_t)(g*27 + t)*4 + ch)*128 + bo*8 + ol)*32 + i] = v;
    }
}

// ============================================================
// Kernel 1: separable FIR  x(2,128,48^3) fp32 -> y bf16
// y layout: yb[n][icq8=16][sp=49^3][8ic]  (16-B groups)
// (unchanged this round — attribution on conv change)
// ============================================================
__global__ __launch_bounds__(256, 3) void fir_y_bf16(
    const float* __restrict__ x, unsigned short* __restrict__ yb)
{
    __shared__ float xs[121*48];             // 23232 B  [(d*11+y)][48]
    __shared__ unsigned short ysl[4*2401];   // 19208 B  [ic][sp(7,7,49)]

    const int tid  = threadIdx.x;
    const int wave = tid >> 6, lane = tid & 63;
    const int tz = blockIdx.x / 7, ty = blockIdx.x % 7;
    const int z0 = tz*7, y0 = ty*7;
    const int icg = blockIdx.y;              // 0..31 (4 ics each)
    const int n   = blockIdx.z;

    const size_t xbase = ((size_t)n*ICn + icg*4) * (size_t)(ISn*ISn*ISn);

    floatx4 pf[6];
    int   cc[6], rowoff[6];
    bool  vld[6];
    #pragma unroll
    for (int s = 0; s < 6; ++s) {
        int idx = tid + 256*s;
        int r = idx / 12, c = idx - r*12;
        if (idx < 1452) {
            int d = r/11, yy = r - d*11;
            int gz = z0 - 3 + d, gy = y0 - 3 + yy;
            bool ok = ((unsigned)gz < 48u) && ((unsigned)gy < 48u);
            vld[s] = ok;
            rowoff[s] = r*48 + 4*c;
            cc[s] = ok ? ((gz*ISn + gy)*ISn + 4*c) : 0;
        } else { vld[s] = false; rowoff[s] = 0; cc[s] = 0; }
    }

    {
        const float* xin = x + xbase;
        #pragma unroll
        for (int s = 0; s < 6; ++s) {
            floatx4 v = {0.f,0.f,0.f,0.f};
            if (vld[s]) v = *(const floatx4*)(xin + cc[s]);
            pf[s] = v;
        }
    }

    for (int ic = 0; ic < 4; ++ic) {
        #pragma unroll
        for (int s = 0; s < 5; ++s)
            *(floatx4*)(xs + rowoff[s]) = pf[s];
        if (tid < 172) *(floatx4*)(xs + rowoff[5]) = pf[5];
        if (ic < 3) {
            const float* xin = x + xbase + (size_t)(ic+1)*(ISn*ISn*ISn);
            #pragma unroll
            for (int s = 0; s < 6; ++s) {
                floatx4 v = {0.f,0.f,0.f,0.f};
                if (vld[s]) v = *(const floatx4*)(xin + cc[s]);
                pf[s] = v;
            }
        }
        __syncthreads();

        const int xp = lane;
        for (int zl = wave; zl < 7; zl += 4) {
            float g[11];
            if (xp < 48) {
                const float* col = xs + zl*528 + xp;
                #pragma unroll
                for (int Y = 0; Y < 11; ++Y) {
                    const float* q = col + Y*48;
                    g[Y] = K0f*(q[0] + q[4*528]) + K1f*(q[528] + q[2*528] + q[3*528]);
                }
            } else {
                #pragma unroll
                for (int Y = 0; Y < 11; ++Y) g[Y] = 0.f;
            }
            #pragma unroll
            for (int yl = 0; yl < 7; ++yl) {
                float h = K0f*(g[yl] + g[yl+4]) + K1f*(g[yl+1] + g[yl+2] + g[yl+3]);
                float hm3 = __shfl(h, (lane + 61) & 63);
                float hm2 = __shfl(h, (lane + 62) & 63);
                float hm1 = __shfl(h, (lane + 63) & 63);
                float hp1 = __shfl(h, (lane + 1) & 63);
                float acc = K0f*(hm3 + hp1) + K1f*(hm2 + hm1 + h);
                if (lane < 49)
                    ysl[ic*2401 + (zl*7 + yl)*49 + lane] = f2bf(acc);
            }
        }
        __syncthreads();
    }

    const size_t ybase = ((size_t)(n*16 + (icg >> 1))) * YV * 8 + (size_t)(icg & 1) * 4;
    for (int idx = tid; idx < 2401; idx += 256) {
        unsigned u0 = (unsigned)ysl[idx]        | ((unsigned)ysl[2401 + idx] << 16);
        unsigned u1 = (unsigned)ysl[4802 + idx] | ((unsigned)ysl[7203 + idx] << 16);
        int zl = idx / 343; int rem = idx - zl*343;
        int yl = rem / 49;  int u = rem - yl*49;
        size_t g_sp = (size_t)(z0+zl)*2401 + (size_t)(y0+yl)*49 + u;
        *(uint2*)(yb + ybase + g_sp*8) = make_uint2(u0, u1);
    }
}

// ============================================================
// per-wave tap-range compute: 4 mi (oc) x 8 ni (od 0..7), taps [T0,T1)
// 32 MFMAs per A-load-group: 160cy of MFMA issue covers L2 latency.
// A prefetched 2 taps ahead, 3 rotating buffers (static idx, full unroll)
// ============================================================
#define SLABZ 17
#define SLABSP (SLABZ*81)      // 1377
template<int T0, int T1>
static __device__ __forceinline__ void do_taps(
    const short8* __restrict__ wt8, int A0,
    const unsigned short* __restrict__ ys3,
    int quad, int oh2, int ow2,
    floatx4 (&acc)[4][8])
{
    short8 Ab[3][4];
    #pragma unroll
    for (int mi = 0; mi < 4; ++mi) Ab[0][mi] = wt8[A0 + T0*2048 + mi*64];
    #pragma unroll
    for (int mi = 0; mi < 4; ++mi) Ab[1][mi] = wt8[A0 + (T0+1)*2048 + mi*64];
    #pragma unroll
    for (int t = T0; t < T1; ++t) {
        const int k = t - T0;
        if (t + 2 < T1) {
            #pragma unroll
            for (int mi = 0; mi < 4; ++mi)
                Ab[(k+2)%3][mi] = wt8[A0 + (t+2)*2048 + mi*64];
        }
        const int a  = t / 9;
        const int b2 = (t / 3) % 3;
        const int c  = t % 3;
        #pragma unroll
        for (int nh = 0; nh < 2; ++nh) {           // split B regs: 4 at a time
            short8 B[4];
            #pragma unroll
            for (int nj = 0; nj < 4; ++nj) {
                const int ni = nh*4 + nj;
                const int zs = 2*ni + a;           // od = ni, 0..16
                const int sp = zs*81 + (oh2 + b2)*9 + ow2 + c;
                B[nj] = *(const short8*)(&ys3[((size_t)quad*SLABSP + sp)*8]);
            }
            #pragma unroll
            for (int mi = 0; mi < 4; ++mi)
                #pragma unroll
                for (int nj = 0; nj < 4; ++nj)
                    acc[mi][nh*4+nj] = __builtin_amdgcn_mfma_f32_16x16x32_bf16(
                        Ab[k%3][mi], B[nj], acc[mi][nh*4+nj], 0, 0, 0);
        }
    }
}

// ============================================================
// Kernel 2: conv via MFMA.  out(2,256,24^3) fp32
// block = 128 oc x 128 pts (4x4x8-z out tile), 8 waves
// = 2(oc half wm) x 4(tap quarter wq). Each A fragment loaded by ONE
// wave per oc-half and amortized over 32 MFMAs (was 16) -> A L2 traffic
// per output halved (764->382 MB) and per-tap latency fully covered.
// Slab: 4 icq x 17x9x9 sp x 16B = 88.1 KB LDS, 1 block/CU (8 waves).
// wq partials reduced through LDS at the end (3 rounds of 64 KB).
// ============================================================
__global__ __launch_bounds__(512, 2) void conv_mfma(
    const unsigned short* __restrict__ wt,
    const unsigned short* __restrict__ yb,
    const float* __restrict__ bias,
    float* __restrict__ out)
{
    __shared__ unsigned short ys3[4*SLABSP*8];   // 88128 B, entry idx at byte idx*16

    const int tid  = threadIdx.x;
    const int wav  = tid >> 6;      // 0..7
    const int lane = tid & 63;
    const int quad = lane >> 4;
    const int m    = lane & 15;
    const int wm   = wav & 1;       // oc half
    const int wq   = wav >> 1;      // tap quarter 0..3

    // ---- XCD-chunked remap: consecutive same-XCD blocks share (sidx) g-pair ----
    const int bx0 = blockIdx.x;            // 0..215
    const int xcd = bx0 & 7;
    const int u   = bx0 >> 3;              // 0..26
    const int v   = xcd*27 + u;            // 0..215 bijective
    const int g    = v & 1;                // ocg
    const int sidx = v >> 1;               // spatial tile 0..107
    const int n    = blockIdx.z;

    const int td = sidx / 36; int r0 = sidx - td*36;   // td 0..2 (od tile of 8)
    const int th = r0 / 6;  const int tw = r0 - th*6;
    const int oc0 = g * 128;

    const int oh2 = (m >> 2) * 2;
    const int ow2 = (m & 3) * 2;

    floatx4 acc[4][8];
    #pragma unroll
    for (int mi = 0; mi < 4; ++mi) {
        floatx4 bv = {0.f, 0.f, 0.f, 0.f};
        if (wq == 0)
            bv = *(const floatx4*)(bias + oc0 + wm*64 + mi*16 + quad*4);
        #pragma unroll
        for (int ni = 0; ni < 8; ++ni) acc[mi][ni] = bv;
    }

    const short8* wt8 = (const short8*)wt;
    const int gz0 = 16*td, gy0 = 8*th, gx0 = 8*tw;

    // ---- per-lane global offsets for the 11 staging slots (once) ----
    // entry idx = s*512 + tid -> (icq = idx/1377, sp = idx%1377)
    const unsigned short* ybn = yb + (size_t)n * 16 * YV * 8;
    unsigned goff[11];
    #pragma unroll
    for (int s = 0; s < 11; ++s) {
        int idx = s*512 + tid;
        int i2 = (idx < 4*SLABSP) ? idx : 0;
        int icq = i2 / SLABSP, sp = i2 - icq*SLABSP;
        int zs = sp / 81; int r = sp - zs*81; int ysv = r / 9; int xsv = r - ysv*9;
        unsigned g_sp = (unsigned)(gz0 + zs)*2401u
                      + (unsigned)(gy0 + ysv)*49u + (unsigned)(gx0 + xsv);
        goff[s] = ((unsigned)icq*(unsigned)YV + g_sp) * 8u;   // ushort units
    }

    for (int chk = 0; chk < 4; ++chk) {
        if (chk) __syncthreads();          // prev compute done -> LDS free
        // ---- issue 11 async 16B copies: global -> LDS (no VGPR staging) ----
        {
            const unsigned short* src = ybn + (size_t)chk * 4u * (size_t)YV * 8u;
            #pragma unroll
            for (int s = 0; s < 11; ++s) {
                if (s < 10 || tid < 388)   // entries 5508.. absent
                    async_copy16(ys3 + ((size_t)(s*512 + wav*64))*8u, src + goff[s]);
            }
        }
        __syncthreads();                    // vmcnt(0) drain: LDS ready

        const int A0 = (g*108 + chk)*512 + (wm*64 + m)*4 + quad;  // short8 units
        if      (wq == 0) do_taps< 0,  7>(wt8, A0, ys3, quad, oh2, ow2, acc);
        else if (wq == 1) do_taps< 7, 14>(wt8, A0, ys3, quad, oh2, ow2, acc);
        else if (wq == 2) do_taps<14, 21>(wt8, A0, ys3, quad, oh2, ow2, acc);
        else              do_taps<21, 27>(wt8, A0, ys3, quad, oh2, ow2, acc);
    }

    // ---- reduce wq partials through LDS (ys3 dead; 64 KB region) ----
    float* red = (float*)ys3;
    // offset per (wm, mi, ni, lane): contiguous 64 KB
    const int roff = (((wm*4 + 0)*8 + 0)*64 + lane)*4;  // base; mi/ni added below
    __syncthreads();
    if (wq == 1) {
        #pragma unroll
        for (int mi = 0; mi < 4; ++mi)
            #pragma unroll
            for (int ni = 0; ni < 8; ++ni)
                *(floatx4*)(red + roff + ((mi*8 + ni)*64)*4) = acc[mi][ni];
    }
    __syncthreads();
    if (wq == 0) {
        #pragma unroll
        for (int mi = 0; mi < 4; ++mi)
            #pragma unroll
            for (int ni = 0; ni < 8; ++ni)
                acc[mi][ni] = acc[mi][ni] + *(const floatx4*)(red + roff + ((mi*8 + ni)*64)*4);
    }
    __syncthreads();
    if (wq == 3) {
        #pragma unroll
        for (int mi = 0; mi < 4; ++mi)
            #pragma unroll
            for (int ni = 0; ni < 8; ++ni)
                *(floatx4*)(red + roff + ((mi*8 + ni)*64)*4) = acc[mi][ni];
    }
    __syncthreads();
    if (wq == 2) {
        #pragma unroll
        for (int mi = 0; mi < 4; ++mi)
            #pragma unroll
            for (int ni = 0; ni < 8; ++ni)
                acc[mi][ni] = acc[mi][ni] + *(const floatx4*)(red + roff + ((mi*8 + ni)*64)*4);
    }
    __syncthreads();
    if (wq == 2) {
        #pragma unroll
        for (int mi = 0; mi < 4; ++mi)
            #pragma unroll
            for (int ni = 0; ni < 8; ++ni)
                *(floatx4*)(red + roff + ((mi*8 + ni)*64)*4) = acc[mi][ni];
    }
    __syncthreads();
    if (wq == 0) {
        const int ohl = m >> 2, owl = m & 3;
        #pragma unroll
        for (int mi = 0; mi < 4; ++mi) {
            #pragma unroll
            for (int ni = 0; ni < 8; ++ni) {
                floatx4 vv = acc[mi][ni]
                    + *(const floatx4*)(red + roff + ((mi*8 + ni)*64)*4);
                #pragma unroll
                for (int r = 0; r < 4; ++r) {
                    const int oc = oc0 + wm*64 + mi*16 + quad*4 + r;
                    size_t addr = ((((size_t)n*OCn + oc)*OSn + td*8 + ni)*OSn + th*4 + ohl)*OSn
                                  + tw*4 + owl;
                    out[addr] = vv[r];
                }
            }
        }
    }
}

// ============================================================
// Fallback (round-1 fused fp32 kernel) if ws too small
// ============================================================
#define TD 4
#define TH 4
#define TW 8
#define XD 13
#define XH 13
#define XW 21
#define YW 17
#define YD 9
#define YH 9
#define XS_LEN (XD*XH*XW)
#define AS_OFF XS_LEN
#define AS_LEN (XD*XH*YW)
#define BS_OFF (AS_OFF + AS_LEN)
#define BS_LEN (XD*YH*YW)
#define WS_OFF 8412
#define WROW 136
#define LDS_TOT (WS_OFF + 27*WROW)

__global__ __launch_bounds__(256) void conv_down3d_fused(
    const float* __restrict__ x, const float* __restrict__ w,
    const float* __restrict__ bias, float* __restrict__ out)
{
    __shared__ float lds[LDS_TOT];
    float* xs = lds;
    float* as = lds + AS_OFF;
    float* bs = lds + BS_OFF;
    float* ws = lds + WS_OFF;
    float* ys = lds;

    const int tid = threadIdx.x;
    int s = blockIdx.x;
    const int tw = s % 3; s /= 3;
    const int th = s % 6; const int td = s / 6;
    const int od0 = td*TD, oh0 = th*TH, ow0 = tw*TW;
    const int oc0 = blockIdx.y * 128;
    const int n   = blockIdx.z;
    const int og = tid >> 4;
    const int pg = tid & 15;
    const int od = pg >> 2;
    const int oh = pg & 3;

    float acc[8][8];
    #pragma unroll
    for (int o = 0; o < 8; ++o) {
        const float bv = bias[oc0 + og*8 + o];
        #pragma unroll
        for (int p = 0; p < 8; ++p) acc[o][p] = bv;
    }

    const int x0d = 2*od0 - 3, x0h = 2*oh0 - 3, x0w = 2*ow0 - 3;
    const float* xn = x + (size_t)n * ICn * (ISn*ISn*ISn);
    const float* wg = w + (size_t)oc0 * (ICn*27);

    for (int ic = 0; ic < ICn; ++ic) {
        const float* xin = xn + (size_t)ic * (ISn*ISn*ISn);
        for (int idx = tid; idx < XS_LEN; idx += 256) {
            int lz = idx / (XH*XW);
            int r  = idx - lz*(XH*XW);
            int ly = r / XW;
            int lx = r - ly*XW;
            int gz = x0d + lz, gy = x0h + ly, gx = x0w + lx;
            float v = 0.0f;
            if ((unsigned)gz < (unsigned)ISn && (unsigned)gy < (unsigned)ISn &&
                (unsigned)gx < (unsigned)ISn)
                v = xin[((size_t)gz*ISn + gy)*ISn + gx];
            xs[idx] = v;
        }
        for (int idx = tid; idx < 27*128; idx += 256) {
            int oc  = idx / 27;
            int tap = idx - oc*27;
            ws[tap*WROW + oc] = wg[(size_t)oc*(ICn*27) + ic*27 + tap];
        }
        __syncthreads();
        for (int idx = tid; idx < AS_LEN; idx += 256) {
            int z = idx / (XH*YW);
            int r = idx - z*(XH*YW);
            int yy = r / YW;
            int u  = r - yy*YW;
            const float* p0 = &xs[(z*XH + yy)*XW + u];
            as[idx] = K0f*(p0[0] + p0[4]) + K1f*(p0[1] + p0[2] + p0[3]);
        }
        __syncthreads();
        for (int idx = tid; idx < BS_LEN; idx += 256) {
            int z = idx / (YH*YW);
            int r = idx - z*(YH*YW);
            int v = r / YW;
            int u = r - v*YW;
            const float* p0 = &as[(z*XH + v)*YW + u];
            bs[idx] = K0f*(p0[0] + p0[4*YW]) + K1f*(p0[YW] + p0[2*YW] + p0[3*YW]);
        }
        __syncthreads();
        for (int idx = tid; idx < YD*YH*YW; idx += 256) {
            int t = idx / (YH*YW);
            int r = idx - t*(YH*YW);
            int v = r / YW;
            int u = r - v*YW;
            const float* p0 = &bs[(t*YH + v)*YW + u];
            ys[idx] = K0f*(p0[0] + p0[4*(YH*YW)]) +
                      K1f*(p0[YH*YW] + p0[2*(YH*YW)] + p0[3*(YH*YW)]);
        }
        __syncthreads();
        #pragma unroll
        for (int a = 0; a < 3; ++a) {
            #pragma unroll
            for (int b = 0; b < 3; ++b) {
                const float* yrow = &ys[((2*od + a)*YH + (2*oh + b))*YW];
                #pragma unroll
                for (int c = 0; c < 3; ++c) {
                    float yv[8];
                    #pragma unroll
                    for (int p = 0; p < 8; ++p) yv[p] = yrow[2*p + c];
                    const float* wrow = &ws[(a*9 + b*3 + c)*WROW + og*8];
                    float wv[8];
                    #pragma unroll
                    for (int o = 0; o < 8; ++o) wv[o] = wrow[o];
                    #pragma unroll
                    for (int o = 0; o < 8; ++o)
                        #pragma unroll
                        for (int p = 0; p < 8; ++p)
                            acc[o][p] += wv[o] * yv[p];
                }
            }
        }
        __syncthreads();
    }
    #pragma unroll
    for (int o = 0; o < 8; ++o) {
        size_t base = ((((size_t)n*OCn + oc0 + og*8 + o)*OSn + (od0+od))*OSn + (oh0+oh))*OSn + ow0;
        float4 v0 = make_float4(acc[o][0], acc[o][1], acc[o][2], acc[o][3]);
        float4 v1 = make_float4(acc[o][4], acc[o][5], acc[o][6], acc[o][7]);
        *(float4*)(out + base)     = v0;
        *(float4*)(out + base + 4) = v1;
    }
}

// ============================================================
extern "C" void kernel_launch(void* const* d_in, const int* in_sizes, int n_in,
                              void* d_out, int out_size, void* d_ws, size_t ws_size,
                              hipStream_t stream) {
    const float* x    = (const float*)d_in[0];
    const float* w    = (const float*)d_in[1];
    const float* bias = (const float*)d_in[2];
    float* out        = (float*)d_out;

    const size_t Y_OFF    = 2097152;                      // 2 MB aligned
    const size_t Y_BYTES  = (size_t)2 * 16 * YV * 8 * 2;  // 60.2 MB
    const size_t WS_NEED  = Y_OFF + Y_BYTES;

    if (ws_size < WS_NEED) {
        dim3 grid(6*6*3, OCn/128, 2);
        hipLaunchKernelGGL(conv_down3d_fused, grid, dim3(256), 0, stream, x, w, bias, out);
        return;
    }

    unsigned short* wt = (unsigned short*)d_ws;
    unsigned short* yb = (unsigned short*)((char*)d_ws + Y_OFF);

    hipLaunchKernelGGL(w_pack,     dim3(32),         dim3(256), 0, stream, w, wt);
    hipLaunchKernelGGL(fir_y_bf16, dim3(49, 32, 2),  dim3(256), 0, stream, x, yb);
    hipLaunchKernelGGL(conv_mfma,  dim3(216, 1, 2),  dim3(512), 0, stream, wt, yb, bias, out);
}

// Round 6
// 364.858 us; speedup vs baseline: 1.1330x; 1.1330x over previous
//
#include <hip/hip_runtime.h>

// ---------------- problem constants ----------------
#define ICn 128
#define OCn 256
#define ISn 48      // x spatial
#define OSn 24      // out spatial
#define YV  117649  // 49^3
#define K0f (1.0f/11.0f)
#define K1f (3.0f/11.0f)

typedef short  short8  __attribute__((ext_vector_type(8)));
typedef float  floatx4 __attribute__((ext_vector_type(4)));

static __device__ __forceinline__ unsigned short f2bf(float f) {
    union { float f; unsigned u; } v; v.f = f;
    unsigned r = (v.u + 0x7FFF + ((v.u >> 16) & 1)) >> 16;   // RNE
    return (unsigned short)r;
}

// async 16B global -> LDS (dest = wave-uniform base + lane*16)
static __device__ __forceinline__ void async_copy16(
    unsigned short* lds_base, const unsigned short* gsrc) {
    __builtin_amdgcn_global_load_lds(
        (const __attribute__((address_space(1))) void*)gsrc,
        (__attribute__((address_space(3))) void*)lds_base, 16, 0, 0);
}

// ============================================================
// Kernel 0: repack w (fp32, [256][128][3][3][3]) -> bf16 wt
// wt layout: [g=2][tap=27][ch=4][oc=128][ic=32]
// NEW: 256 blocks (one oc each) instead of 32 — was 12.5% chip
// utilization with a conflicted stride-54B LDS transpose.
// ============================================================
__global__ __launch_bounds__(256) void w_pack(
    const float* __restrict__ w, unsigned short* __restrict__ wt)
{
    __shared__ unsigned short lw[3456];   // [ch*32+ic][27] bf16, one oc
    const int tid = threadIdx.x;
    const int oc = blockIdx.x;            // 0..255
    const float* src = w + (size_t)oc * 3456;
    for (int i4 = tid; i4 < 864; i4 += 256) {
        floatx4 v = *(const floatx4*)(src + (size_t)i4*4);
        ushort4 u;
        u.x = f2bf(v.x); u.y = f2bf(v.y); u.z = f2bf(v.z); u.w = f2bf(v.w);
        *(ushort4*)(&lw[i4*4]) = u;
    }
    __syncthreads();
    const int g = oc >> 7, ol = oc & 127;
    for (int idx = tid; idx < 3456; idx += 256) {
        int i  = idx & 31;
        int ch = (idx >> 5) & 3;
        int t  = idx >> 7;
        wt[(((size_t)(g*27 + t)*4 + ch)*128 + ol)*32 + i] = lw[(ch*32 + i)*27 + t];
    }
}

// ============================================================
// Kernel 1: separable FIR  x(2,128,48^3) fp32 -> y bf16
// y layout: yb[n][icq8=16][sp=49^3][8ic]  (16-B groups)
// NEW (T14): next-ic prefetch issued AFTER the first barrier, so the
// barrier's implicit vmcnt(0) no longer drains it synchronously — the
// loads now land under the compute phase and drain at the end barrier.
// ============================================================
__global__ __launch_bounds__(256, 3) void fir_y_bf16(
    const float* __restrict__ x, unsigned short* __restrict__ yb)
{
    __shared__ float xs[121*48];             // 23232 B  [(d*11+y)][48]
    __shared__ unsigned short ysl[4*2401];   // 19208 B  [ic][sp(7,7,49)]

    const int tid  = threadIdx.x;
    const int wave = tid >> 6, lane = tid & 63;
    const int tz = blockIdx.x / 7, ty = blockIdx.x % 7;
    const int z0 = tz*7, y0 = ty*7;
    const int icg = blockIdx.y;              // 0..31 (4 ics each)
    const int n   = blockIdx.z;

    const size_t xbase = ((size_t)n*ICn + icg*4) * (size_t)(ISn*ISn*ISn);

    floatx4 pf[6];
    int   cc[6], rowoff[6];
    bool  vld[6];
    #pragma unroll
    for (int s = 0; s < 6; ++s) {
        int idx = tid + 256*s;
        int r = idx / 12, c = idx - r*12;
        if (idx < 1452) {
            int d = r/11, yy = r - d*11;
            int gz = z0 - 3 + d, gy = y0 - 3 + yy;
            bool ok = ((unsigned)gz < 48u) && ((unsigned)gy < 48u);
            vld[s] = ok;
            rowoff[s] = r*48 + 4*c;
            cc[s] = ok ? ((gz*ISn + gy)*ISn + 4*c) : 0;
        } else { vld[s] = false; rowoff[s] = 0; cc[s] = 0; }
    }

    {
        const float* xin = x + xbase;
        #pragma unroll
        for (int s = 0; s < 6; ++s) {
            floatx4 v = {0.f,0.f,0.f,0.f};
            if (vld[s]) v = *(const floatx4*)(xin + cc[s]);
            pf[s] = v;
        }
    }

    for (int ic = 0; ic < 4; ++ic) {
        // ---- write staged tile to LDS ----
        #pragma unroll
        for (int s = 0; s < 5; ++s)
            *(floatx4*)(xs + rowoff[s]) = pf[s];
        if (tid < 172) *(floatx4*)(xs + rowoff[5]) = pf[5];
        __syncthreads();                 // xs ready (drains ds_writes)

        // ---- T14: issue prefetch for next ic AFTER the barrier ----
        if (ic < 3) {
            const float* xin = x + xbase + (size_t)(ic+1)*(ISn*ISn*ISn);
            #pragma unroll
            for (int s = 0; s < 6; ++s) {
                floatx4 v = {0.f,0.f,0.f,0.f};
                if (vld[s]) v = *(const floatx4*)(xin + cc[s]);
                pf[s] = v;
            }
        }

        // ---- compute: z-filter to g[11], y-filter in regs, x via shfl ----
        const int xp = lane;
        for (int zl = wave; zl < 7; zl += 4) {
            float g[11];
            if (xp < 48) {
                const float* col = xs + zl*528 + xp;
                #pragma unroll
                for (int Y = 0; Y < 11; ++Y) {
                    const float* q = col + Y*48;
                    g[Y] = K0f*(q[0] + q[4*528]) + K1f*(q[528] + q[2*528] + q[3*528]);
                }
            } else {
                #pragma unroll
                for (int Y = 0; Y < 11; ++Y) g[Y] = 0.f;
            }
            #pragma unroll
            for (int yl = 0; yl < 7; ++yl) {
                float h = K0f*(g[yl] + g[yl+4]) + K1f*(g[yl+1] + g[yl+2] + g[yl+3]);
                float hm3 = __shfl(h, (lane + 61) & 63);
                float hm2 = __shfl(h, (lane + 62) & 63);
                float hm1 = __shfl(h, (lane + 63) & 63);
                float hp1 = __shfl(h, (lane + 1) & 63);
                float acc = K0f*(hm3 + hp1) + K1f*(hm2 + hm1 + h);
                if (lane < 49)
                    ysl[ic*2401 + (zl*7 + yl)*49 + lane] = f2bf(acc);
            }
        }
        __syncthreads();                 // compute done; prefetch drains here
    }

    const size_t ybase = ((size_t)(n*16 + (icg >> 1))) * YV * 8 + (size_t)(icg & 1) * 4;
    for (int idx = tid; idx < 2401; idx += 256) {
        unsigned u0 = (unsigned)ysl[idx]        | ((unsigned)ysl[2401 + idx] << 16);
        unsigned u1 = (unsigned)ysl[4802 + idx] | ((unsigned)ysl[7203 + idx] << 16);
        int zl = idx / 343; int rem = idx - zl*343;
        int yl = rem / 49;  int u = rem - yl*49;
        size_t g_sp = (size_t)(z0+zl)*2401 + (size_t)(y0+yl)*49 + u;
        *(uint2*)(yb + ybase + g_sp*8) = make_uint2(u0, u1);
    }
}

// ============================================================
// per-wave tap-range compute: 4 mi (oc) x 4 ni (od 0..3), taps [T0,T1)
// A prefetched 2 taps ahead, 3 rotating buffers (static idx, full unroll)
// (round-3 structure: measured 153 us; round-5 128-pt variant spilled)
// ============================================================
template<int T0, int T1>
static __device__ __forceinline__ void do_taps(
    const short8* __restrict__ wt8, int A0,
    const unsigned short* __restrict__ ys3,
    int quad, int oh2, int ow2,
    floatx4 (&acc)[4][4])
{
    short8 Ab[3][4];
    #pragma unroll
    for (int mi = 0; mi < 4; ++mi) Ab[0][mi] = wt8[A0 + T0*2048 + mi*64];
    #pragma unroll
    for (int mi = 0; mi < 4; ++mi) Ab[1][mi] = wt8[A0 + (T0+1)*2048 + mi*64];
    #pragma unroll
    for (int t = T0; t < T1; ++t) {
        const int k = t - T0;
        if (t + 2 < T1) {
            #pragma unroll
            for (int mi = 0; mi < 4; ++mi)
                Ab[(k+2)%3][mi] = wt8[A0 + (t+2)*2048 + mi*64];
        }
        const int a  = t / 9;
        const int b2 = (t / 3) % 3;
        const int c  = t % 3;
        short8 B[4];
        #pragma unroll
        for (int ni = 0; ni < 4; ++ni) {
            const int zs = 2*ni + a;                       // od = ni
            const int sp = (zs*9 + oh2 + b2)*9 + ow2 + c;
            B[ni] = *(const short8*)(&ys3[((size_t)quad*729 + sp)*8]);
        }
        #pragma unroll
        for (int mi = 0; mi < 4; ++mi)
            #pragma unroll
            for (int ni = 0; ni < 4; ++ni)
                acc[mi][ni] = __builtin_amdgcn_mfma_f32_16x16x32_bf16(
                    Ab[k%3][mi], B[ni], acc[mi][ni], 0, 0, 0);
    }
}

// ============================================================
// Kernel 2: conv via MFMA.  out(2,256,24^3) fp32
// block: 128 oc x 64 pts; 4 waves = 2(oc-half wm) x 2(tap-range wq)
// (reverted to round-3: 153 us measured; tap-split halves A traffic,
//  async global_load_lds staging, XCD g-pairing)
// ============================================================
__global__ __launch_bounds__(256, 3) void conv_mfma(
    const unsigned short* __restrict__ wt,
    const unsigned short* __restrict__ yb,
    const float* __restrict__ bias,
    float* __restrict__ out)
{
    __shared__ unsigned short ys3[4*729*8];   // 46656 B, entry idx at byte idx*16

    const int tid  = threadIdx.x;
    const int wav  = tid >> 6;
    const int lane = tid & 63;
    const int quad = lane >> 4;
    const int m    = lane & 15;
    const int wm   = wav & 1;       // oc half
    const int wq   = wav >> 1;      // tap-range half

    // ---- XCD-paired spatial/ocg remap ----
    const int bx0 = blockIdx.x;            // 0..431
    const int xcd = bx0 & 7;
    const int u   = bx0 >> 3;              // 0..53
    const int sidx = xcd*27 + (u >> 1);    // spatial tile 0..215
    const int g    = u & 1;                // ocg
    const int n    = blockIdx.z;

    const int td = sidx / 36; int r0 = sidx - td*36;
    const int th = r0 / 6;  const int tw = r0 - th*6;
    const int oc0 = g * 128;

    const int oh2 = (m >> 2) * 2;
    const int ow2 = (m & 3) * 2;

    floatx4 acc[4][4];
    #pragma unroll
    for (int mi = 0; mi < 4; ++mi) {
        floatx4 bv = {0.f, 0.f, 0.f, 0.f};
        if (wq == 0)
            bv = *(const floatx4*)(bias + oc0 + wm*64 + mi*16 + quad*4);
        #pragma unroll
        for (int ni = 0; ni < 4; ++ni) acc[mi][ni] = bv;
    }

    const short8* wt8 = (const short8*)wt;
    const int gz0 = 8*td, gy0 = 8*th, gx0 = 8*tw;

    // ---- per-lane global offsets for the 12 staging slots (once) ----
    const unsigned short* ybn = yb + (size_t)n * 16 * YV * 8;
    unsigned goff[12];
    #pragma unroll
    for (int s = 0; s < 12; ++s) {
        int idx = s*256 + tid;
        int i2 = (idx < 2916) ? idx : 0;
        int icq = i2 / 729, sp = i2 - icq*729;
        int zs = sp / 81; int r = sp - zs*81; int ysv = r / 9; int xsv = r - ysv*9;
        unsigned g_sp = (unsigned)(gz0 + zs)*2401u
                      + (unsigned)(gy0 + ysv)*49u + (unsigned)(gx0 + xsv);
        goff[s] = ((unsigned)icq*(unsigned)YV + g_sp) * 8u;   // ushort units
    }

    for (int chk = 0; chk < 4; ++chk) {
        if (chk) __syncthreads();          // prev compute done -> LDS free
        // ---- issue 12 async 16B copies: global -> LDS (no VGPR staging) ----
        {
            const unsigned short* src = ybn + (size_t)chk * 4u * (size_t)YV * 8u;
            unsigned short* dstw = ys3 + ((size_t)wav * 64u) * 8u;  // wave-uniform
            #pragma unroll
            for (int s = 0; s < 12; ++s) {
                if (s < 11 || tid < 100)   // entries 2916.. are absent
                    async_copy16(dstw + (size_t)s * 2048u, src + goff[s]);
            }
        }
        __syncthreads();                    // vmcnt(0) drain: LDS ready

        const int A0 = (g*108 + chk)*512 + (wm*64 + m)*4 + quad;  // short8 units
        if (wq == 0)
            do_taps<0, 14>(wt8, A0, ys3, quad, oh2, ow2, acc);
        else
            do_taps<14, 27>(wt8, A0, ys3, quad, oh2, ow2, acc);
    }

    // ---- reduce wq1 -> wq0 through LDS (ys3 is dead), then store ----
    __syncthreads();
    float* red = (float*)ys3;              // 32 KB used
    if (wq == 1) {
        #pragma unroll
        for (int mi = 0; mi < 4; ++mi)
            #pragma unroll
            for (int ni = 0; ni < 4; ++ni)
                *(floatx4*)(red + ((wm*16 + mi*4 + ni)*64 + lane)*4) = acc[mi][ni];
    }
    __syncthreads();
    if (wq == 0) {
        const int ohl = m >> 2, owl = m & 3;
        #pragma unroll
        for (int mi = 0; mi < 4; ++mi) {
            #pragma unroll
            for (int ni = 0; ni < 4; ++ni) {
                floatx4 v = acc[mi][ni]
                    + *(const floatx4*)(red + ((wm*16 + mi*4 + ni)*64 + lane)*4);
                #pragma unroll
                for (int r = 0; r < 4; ++r) {
                    const int oc = oc0 + wm*64 + mi*16 + quad*4 + r;
                    size_t addr = ((((size_t)n*OCn + oc)*OSn + td*4 + ni)*OSn + th*4 + ohl)*OSn
                                  + tw*4 + owl;
                    out[addr] = v[r];
                }
            }
        }
    }
}

// ============================================================
// Fallback (round-1 fused fp32 kernel) if ws too small
// ============================================================
#define TD 4
#define TH 4
#define TW 8
#define XD 13
#define XH 13
#define XW 21
#define YW 17
#define YD 9
#define YH 9
#define XS_LEN (XD*XH*XW)
#define AS_OFF XS_LEN
#define AS_LEN (XD*XH*YW)
#define BS_OFF (AS_OFF + AS_LEN)
#define BS_LEN (XD*YH*YW)
#define WS_OFF 8412
#define WROW 136
#define LDS_TOT (WS_OFF + 27*WROW)

__global__ __launch_bounds__(256) void conv_down3d_fused(
    const float* __restrict__ x, const float* __restrict__ w,
    const float* __restrict__ bias, float* __restrict__ out)
{
    __shared__ float lds[LDS_TOT];
    float* xs = lds;
    float* as = lds + AS_OFF;
    float* bs = lds + BS_OFF;
    float* ws = lds + WS_OFF;
    float* ys = lds;

    const int tid = threadIdx.x;
    int s = blockIdx.x;
    const int tw = s % 3; s /= 3;
    const int th = s % 6; const int td = s / 6;
    const int od0 = td*TD, oh0 = th*TH, ow0 = tw*TW;
    const int oc0 = blockIdx.y * 128;
    const int n   = blockIdx.z;
    const int og = tid >> 4;
    const int pg = tid & 15;
    const int od = pg >> 2;
    const int oh = pg & 3;

    float acc[8][8];
    #pragma unroll
    for (int o = 0; o < 8; ++o) {
        const float bv = bias[oc0 + og*8 + o];
        #pragma unroll
        for (int p = 0; p < 8; ++p) acc[o][p] = bv;
    }

    const int x0d = 2*od0 - 3, x0h = 2*oh0 - 3, x0w = 2*ow0 - 3;
    const float* xn = x + (size_t)n * ICn * (ISn*ISn*ISn);
    const float* wg = w + (size_t)oc0 * (ICn*27);

    for (int ic = 0; ic < ICn; ++ic) {
        const float* xin = xn + (size_t)ic * (ISn*ISn*ISn);
        for (int idx = tid; idx < XS_LEN; idx += 256) {
            int lz = idx / (XH*XW);
            int r  = idx - lz*(XH*XW);
            int ly = r / XW;
            int lx = r - ly*XW;
            int gz = x0d + lz, gy = x0h + ly, gx = x0w + lx;
            float v = 0.0f;
            if ((unsigned)gz < (unsigned)ISn && (unsigned)gy < (unsigned)ISn &&
                (unsigned)gx < (unsigned)ISn)
                v = xin[((size_t)gz*ISn + gy)*ISn + gx];
            xs[idx] = v;
        }
        for (int idx = tid; idx < 27*128; idx += 256) {
            int oc  = idx / 27;
            int tap = idx - oc*27;
            ws[tap*WROW + oc] = wg[(size_t)oc*(ICn*27) + ic*27 + tap];
        }
        __syncthreads();
        for (int idx = tid; idx < AS_LEN; idx += 256) {
            int z = idx / (XH*YW);
            int r = idx - z*(XH*YW);
            int yy = r / YW;
            int u  = r - yy*YW;
            const float* p0 = &xs[(z*XH + yy)*XW + u];
            as[idx] = K0f*(p0[0] + p0[4]) + K1f*(p0[1] + p0[2] + p0[3]);
        }
        __syncthreads();
        for (int idx = tid; idx < BS_LEN; idx += 256) {
            int z = idx / (YH*YW);
            int r = idx - z*(YH*YW);
            int v = r / YW;
            int u = r - v*YW;
            const float* p0 = &as[(z*XH + v)*YW + u];
            bs[idx] = K0f*(p0[0] + p0[4*YW]) + K1f*(p0[YW] + p0[2*YW] + p0[3*YW]);
        }
        __syncthreads();
        for (int idx = tid; idx < YD*YH*YW; idx += 256) {
            int t = idx / (YH*YW);
            int r = idx - t*(YH*YW);
            int v = r / YW;
            int u = r - v*YW;
            const float* p0 = &bs[(t*YH + v)*YW + u];
            ys[idx] = K0f*(p0[0] + p0[4*(YH*YW)]) +
                      K1f*(p0[YH*YW] + p0[2*(YH*YW)] + p0[3*(YH*YW)]);
        }
        __syncthreads();
        #pragma unroll
        for (int a = 0; a < 3; ++a) {
            #pragma unroll
            for (int b = 0; b < 3; ++b) {
                const float* yrow = &ys[((2*od + a)*YH + (2*oh + b))*YW];
                #pragma unroll
                for (int c = 0; c < 3; ++c) {
                    float yv[8];
                    #pragma unroll
                    for (int p = 0; p < 8; ++p) yv[p] = yrow[2*p + c];
                    const float* wrow = &ws[(a*9 + b*3 + c)*WROW + og*8];
                    float wv[8];
                    #pragma unroll
                    for (int o = 0; o < 8; ++o) wv[o] = wrow[o];
                    #pragma unroll
                    for (int o = 0; o < 8; ++o)
                        #pragma unroll
                        for (int p = 0; p < 8; ++p)
                            acc[o][p] += wv[o] * yv[p];
                }
            }
        }
        __syncthreads();
    }
    #pragma unroll
    for (int o = 0; o < 8; ++o) {
        size_t base = ((((size_t)n*OCn + oc0 + og*8 + o)*OSn + (od0+od))*OSn + (oh0+oh))*OSn + ow0;
        float4 v0 = make_float4(acc[o][0], acc[o][1], acc[o][2], acc[o][3]);
        float4 v1 = make_float4(acc[o][4], acc[o][5], acc[o][6], acc[o][7]);
        *(float4*)(out + base)     = v0;
        *(float4*)(out + base + 4) = v1;
    }
}

// ============================================================
extern "C" void kernel_launch(void* const* d_in, const int* in_sizes, int n_in,
                              void* d_out, int out_size, void* d_ws, size_t ws_size,
                              hipStream_t stream) {
    const float* x    = (const float*)d_in[0];
    const float* w    = (const float*)d_in[1];
    const float* bias = (const float*)d_in[2];
    float* out        = (float*)d_out;

    const size_t Y_OFF    = 2097152;                      // 2 MB aligned
    const size_t Y_BYTES  = (size_t)2 * 16 * YV * 8 * 2;  // 60.2 MB
    const size_t WS_NEED  = Y_OFF + Y_BYTES;

    if (ws_size < WS_NEED) {
        dim3 grid(6*6*3, OCn/128, 2);
        hipLaunchKernelGGL(conv_down3d_fused, grid, dim3(256), 0, stream, x, w, bias, out);
        return;
    }

    unsigned short* wt = (unsigned short*)d_ws;
    unsigned short* yb = (unsigned short*)((char*)d_ws + Y_OFF);

    hipLaunchKernelGGL(w_pack,     dim3(256),        dim3(256), 0, stream, w, wt);
    hipLaunchKernelGGL(fir_y_bf16, dim3(49, 32, 2),  dim3(256), 0, stream, x, yb);
    hipLaunchKernelGGL(conv_mfma,  dim3(432, 1, 2),  dim3(256), 0, stream, wt, yb, bias, out);
}

// Round 7
// 295.978 us; speedup vs baseline: 1.3967x; 1.2327x over previous
//
#include <hip/hip_runtime.h>

// ---------------- problem constants ----------------
#define ICn 128
#define OCn 256
#define ISn 48      // x spatial
#define OSn 24      // out spatial
#define YV  117649  // 49^3
#define K0f (1.0f/11.0f)
#define K1f (3.0f/11.0f)

typedef short  short8  __attribute__((ext_vector_type(8)));
typedef float  floatx4 __attribute__((ext_vector_type(4)));

static __device__ __forceinline__ unsigned short f2bf(float f) {
    union { float f; unsigned u; } v; v.f = f;
    unsigned r = (v.u + 0x7FFF + ((v.u >> 16) & 1)) >> 16;   // RNE
    return (unsigned short)r;
}

// async 16B global -> LDS (dest = wave-uniform base + lane*16)
static __device__ __forceinline__ void async_copy16(
    unsigned short* lds_base, const unsigned short* gsrc) {
    __builtin_amdgcn_global_load_lds(
        (const __attribute__((address_space(1))) void*)gsrc,
        (__attribute__((address_space(3))) void*)lds_base, 16, 0, 0);
}

// ============================================================
// Kernel 0: repack w (fp32, [256][128][3][3][3]) -> bf16 wt
// wt layout: [g=2][tap=27][ch=4][oc=128][ic=32]
// 256 blocks (one oc each).
// ============================================================
__global__ __launch_bounds__(256) void w_pack(
    const float* __restrict__ w, unsigned short* __restrict__ wt)
{
    __shared__ unsigned short lw[3456];   // [ch*32+ic][27] bf16, one oc
    const int tid = threadIdx.x;
    const int oc = blockIdx.x;            // 0..255
    const float* src = w + (size_t)oc * 3456;
    for (int i4 = tid; i4 < 864; i4 += 256) {
        floatx4 v = *(const floatx4*)(src + (size_t)i4*4);
        ushort4 u;
        u.x = f2bf(v.x); u.y = f2bf(v.y); u.z = f2bf(v.z); u.w = f2bf(v.w);
        *(ushort4*)(&lw[i4*4]) = u;
    }
    __syncthreads();
    const int g = oc >> 7, ol = oc & 127;
    for (int idx = tid; idx < 3456; idx += 256) {
        int i  = idx & 31;
        int ch = (idx >> 5) & 3;
        int t  = idx >> 7;
        wt[(((size_t)(g*27 + t)*4 + ch)*128 + ol)*32 + i] = lw[(ch*32 + i)*27 + t];
    }
}

// ============================================================
// Kernel 1: separable FIR  x(2,128,48^3) fp32 -> y bf16
// y layout: yb[n][icq8=16][sp=49^3][8ic]  (16-B groups)
// T14: next-ic prefetch issued AFTER the barrier (lands under compute).
// ============================================================
__global__ __launch_bounds__(256, 3) void fir_y_bf16(
    const float* __restrict__ x, unsigned short* __restrict__ yb)
{
    __shared__ float xs[121*48];             // 23232 B  [(d*11+y)][48]
    __shared__ unsigned short ysl[4*2401];   // 19208 B  [ic][sp(7,7,49)]

    const int tid  = threadIdx.x;
    const int wave = tid >> 6, lane = tid & 63;
    const int tz = blockIdx.x / 7, ty = blockIdx.x % 7;
    const int z0 = tz*7, y0 = ty*7;
    const int icg = blockIdx.y;              // 0..31 (4 ics each)
    const int n   = blockIdx.z;

    const size_t xbase = ((size_t)n*ICn + icg*4) * (size_t)(ISn*ISn*ISn);

    floatx4 pf[6];
    int   cc[6], rowoff[6];
    bool  vld[6];
    #pragma unroll
    for (int s = 0; s < 6; ++s) {
        int idx = tid + 256*s;
        int r = idx / 12, c = idx - r*12;
        if (idx < 1452) {
            int d = r/11, yy = r - d*11;
            int gz = z0 - 3 + d, gy = y0 - 3 + yy;
            bool ok = ((unsigned)gz < 48u) && ((unsigned)gy < 48u);
            vld[s] = ok;
            rowoff[s] = r*48 + 4*c;
            cc[s] = ok ? ((gz*ISn + gy)*ISn + 4*c) : 0;
        } else { vld[s] = false; rowoff[s] = 0; cc[s] = 0; }
    }

    {
        const float* xin = x + xbase;
        #pragma unroll
        for (int s = 0; s < 6; ++s) {
            floatx4 v = {0.f,0.f,0.f,0.f};
            if (vld[s]) v = *(const floatx4*)(xin + cc[s]);
            pf[s] = v;
        }
    }

    for (int ic = 0; ic < 4; ++ic) {
        // ---- write staged tile to LDS ----
        #pragma unroll
        for (int s = 0; s < 5; ++s)
            *(floatx4*)(xs + rowoff[s]) = pf[s];
        if (tid < 172) *(floatx4*)(xs + rowoff[5]) = pf[5];
        __syncthreads();                 // xs ready

        // ---- T14: issue prefetch for next ic AFTER the barrier ----
        if (ic < 3) {
            const float* xin = x + xbase + (size_t)(ic+1)*(ISn*ISn*ISn);
            #pragma unroll
            for (int s = 0; s < 6; ++s) {
                floatx4 v = {0.f,0.f,0.f,0.f};
                if (vld[s]) v = *(const floatx4*)(xin + cc[s]);
                pf[s] = v;
            }
        }

        // ---- compute: z-filter to g[11], y-filter in regs, x via shfl ----
        const int xp = lane;
        for (int zl = wave; zl < 7; zl += 4) {
            float g[11];
            if (xp < 48) {
                const float* col = xs + zl*528 + xp;
                #pragma unroll
                for (int Y = 0; Y < 11; ++Y) {
                    const float* q = col + Y*48;
                    g[Y] = K0f*(q[0] + q[4*528]) + K1f*(q[528] + q[2*528] + q[3*528]);
                }
            } else {
                #pragma unroll
                for (int Y = 0; Y < 11; ++Y) g[Y] = 0.f;
            }
            #pragma unroll
            for (int yl = 0; yl < 7; ++yl) {
                float h = K0f*(g[yl] + g[yl+4]) + K1f*(g[yl+1] + g[yl+2] + g[yl+3]);
                float hm3 = __shfl(h, (lane + 61) & 63);
                float hm2 = __shfl(h, (lane + 62) & 63);
                float hm1 = __shfl(h, (lane + 63) & 63);
                float hp1 = __shfl(h, (lane + 1) & 63);
                float acc = K0f*(hm3 + hp1) + K1f*(hm2 + hm1 + h);
                if (lane < 49)
                    ysl[ic*2401 + (zl*7 + yl)*49 + lane] = f2bf(acc);
            }
        }
        __syncthreads();                 // compute done; prefetch drains here
    }

    const size_t ybase = ((size_t)(n*16 + (icg >> 1))) * YV * 8 + (size_t)(icg & 1) * 4;
    for (int idx = tid; idx < 2401; idx += 256) {
        unsigned u0 = (unsigned)ysl[idx]        | ((unsigned)ysl[2401 + idx] << 16);
        unsigned u1 = (unsigned)ysl[4802 + idx] | ((unsigned)ysl[7203 + idx] << 16);
        int zl = idx / 343; int rem = idx - zl*343;
        int yl = rem / 49;  int u = rem - yl*49;
        size_t g_sp = (size_t)(z0+zl)*2401 + (size_t)(y0+yl)*49 + u;
        *(uint2*)(yb + ybase + g_sp*8) = make_uint2(u0, u1);
    }
}

// ============================================================
// per-wave tap-range compute: 2 mi (32 oc) x 8 ni (od 0..7), taps [T0,T1)
// 8 MFMAs per A-load (was 4). A prefetched 2 taps ahead, 3 rot buffers.
// ============================================================
#define SLABZ 17
#define SLABSP (SLABZ*81)      // 1377
template<int T0, int T1>
static __device__ __forceinline__ void do_taps(
    const short8* __restrict__ wt8, int A0,
    const unsigned short* __restrict__ ys3,
    int quad, int oh2, int ow2,
    floatx4 (&acc)[2][8])
{
    short8 Ab[3][2];
    #pragma unroll
    for (int mi = 0; mi < 2; ++mi) Ab[0][mi] = wt8[A0 + T0*2048 + mi*64];
    #pragma unroll
    for (int mi = 0; mi < 2; ++mi) Ab[1][mi] = wt8[A0 + (T0+1)*2048 + mi*64];
    #pragma unroll
    for (int t = T0; t < T1; ++t) {
        const int k = t - T0;
        if (t + 2 < T1) {
            #pragma unroll
            for (int mi = 0; mi < 2; ++mi)
                Ab[(k+2)%3][mi] = wt8[A0 + (t+2)*2048 + mi*64];
        }
        const int a  = t / 9;
        const int b2 = (t / 3) % 3;
        const int c  = t % 3;
        #pragma unroll
        for (int nh = 0; nh < 2; ++nh) {           // B regs: 4 at a time
            short8 B[4];
            #pragma unroll
            for (int nj = 0; nj < 4; ++nj) {
                const int ni = nh*4 + nj;
                const int zs = 2*ni + a;           // od = ni, 0..16
                const int sp = zs*81 + (oh2 + b2)*9 + ow2 + c;
                B[nj] = *(const short8*)(&ys3[((size_t)quad*SLABSP + sp)*8]);
            }
            #pragma unroll
            for (int mi = 0; mi < 2; ++mi)
                #pragma unroll
                for (int nj = 0; nj < 4; ++nj)
                    acc[mi][nh*4+nj] = __builtin_amdgcn_mfma_f32_16x16x32_bf16(
                        Ab[k%3][mi], B[nj], acc[mi][nh*4+nj], 0, 0, 0);
        }
    }
}

// ============================================================
// Kernel 2: conv via MFMA.  out(2,256,24^3) fp32
// block = 128 oc x 128 pts (4x4x8-z out tile), 8 waves
// = 4(oc quarter wm) x 2(tap half wq).
// vs round-5: same tile & staging (correctness-verified), but wave split
// 4x2 keeps per-wave acc at 64 AGPRs (round-3 budget) -> no spill.
// A bytes per output halved vs round-3 (382->191 MB); 8 MFMA per A-load.
// Slab 88.1 KB LDS, 1 block/CU = 2 waves/SIMD (25% occ > measured 19%).
// wq1 -> wq0 partials through LDS (64 KB of dead slab).
// ============================================================
__global__ __launch_bounds__(512, 2) void conv_mfma(
    const unsigned short* __restrict__ wt,
    const unsigned short* __restrict__ yb,
    const float* __restrict__ bias,
    float* __restrict__ out)
{
    __shared__ unsigned short ys3[4*SLABSP*8];   // 88128 B, entry idx at byte idx*16

    const int tid  = threadIdx.x;
    const int wav  = tid >> 6;      // 0..7
    const int lane = tid & 63;
    const int quad = lane >> 4;
    const int m    = lane & 15;
    const int wm   = wav & 3;       // oc quarter 0..3
    const int wq   = wav >> 2;      // tap half 0..1

    // ---- XCD-paired remap: g=0/1 of one spatial tile adjacent on one XCD ----
    const int bx0 = blockIdx.x;            // 0..215
    const int xcd = bx0 & 7;
    const int u   = bx0 >> 3;              // 0..26
    const int v   = xcd*27 + u;            // 0..215 bijective
    const int g    = v & 1;                // ocg
    const int sidx = v >> 1;               // spatial tile 0..107
    const int n    = blockIdx.z;

    const int td = sidx / 36; int r0 = sidx - td*36;   // td 0..2 (od tile of 8)
    const int th = r0 / 6;  const int tw = r0 - th*6;
    const int oc0 = g * 128;

    const int oh2 = (m >> 2) * 2;
    const int ow2 = (m & 3) * 2;

    floatx4 acc[2][8];
    #pragma unroll
    for (int mi = 0; mi < 2; ++mi) {
        floatx4 bv = {0.f, 0.f, 0.f, 0.f};
        if (wq == 0)
            bv = *(const floatx4*)(bias + oc0 + wm*32 + mi*16 + quad*4);
        #pragma unroll
        for (int ni = 0; ni < 8; ++ni) acc[mi][ni] = bv;
    }

    const short8* wt8 = (const short8*)wt;
    const int gz0 = 16*td, gy0 = 8*th, gx0 = 8*tw;

    // ---- per-lane global offsets for the 11 staging slots (once) ----
    // entry idx = s*512 + tid -> (icq = idx/1377, sp = idx%1377)
    const unsigned short* ybn = yb + (size_t)n * 16 * YV * 8;
    unsigned goff[11];
    #pragma unroll
    for (int s = 0; s < 11; ++s) {
        int idx = s*512 + tid;
        int i2 = (idx < 4*SLABSP) ? idx : 0;
        int icq = i2 / SLABSP, sp = i2 - icq*SLABSP;
        int zs = sp / 81; int r = sp - zs*81; int ysv = r / 9; int xsv = r - ysv*9;
        unsigned g_sp = (unsigned)(gz0 + zs)*2401u
                      + (unsigned)(gy0 + ysv)*49u + (unsigned)(gx0 + xsv);
        goff[s] = ((unsigned)icq*(unsigned)YV + g_sp) * 8u;   // ushort units
    }

    for (int chk = 0; chk < 4; ++chk) {
        if (chk) __syncthreads();          // prev compute done -> LDS free
        // ---- issue 11 async 16B copies: global -> LDS (no VGPR staging) ----
        {
            const unsigned short* src = ybn + (size_t)chk * 4u * (size_t)YV * 8u;
            #pragma unroll
            for (int s = 0; s < 11; ++s) {
                if (s < 10 || tid < 388)   // entries 5508.. absent
                    async_copy16(ys3 + ((size_t)(s*512 + wav*64))*8u, src + goff[s]);
            }
        }
        __syncthreads();                    // vmcnt(0) drain: LDS ready

        // A0: (g,chk) base + oc quarter: oc = wm*32 + mi*16 + m; ic8 = quad
        const int A0 = (g*108 + chk)*512 + (wm*32 + m)*4 + quad;  // short8 units
        if (wq == 0)
            do_taps< 0, 14>(wt8, A0, ys3, quad, oh2, ow2, acc);
        else
            do_taps<14, 27>(wt8, A0, ys3, quad, oh2, ow2, acc);
    }

    // ---- reduce wq1 -> wq0 through LDS (ys3 dead; 64 KB used) ----
    __syncthreads();
    float* red = (float*)ys3;
    if (wq == 1) {
        #pragma unroll
        for (int mi = 0; mi < 2; ++mi)
            #pragma unroll
            for (int ni = 0; ni < 8; ++ni)
                *(floatx4*)(red + (((wm*2 + mi)*8 + ni)*64 + lane)*4) = acc[mi][ni];
    }
    __syncthreads();
    if (wq == 0) {
        const int ohl = m >> 2, owl = m & 3;
        #pragma unroll
        for (int mi = 0; mi < 2; ++mi) {
            #pragma unroll
            for (int ni = 0; ni < 8; ++ni) {
                floatx4 vv = acc[mi][ni]
                    + *(const floatx4*)(red + (((wm*2 + mi)*8 + ni)*64 + lane)*4);
                #pragma unroll
                for (int r = 0; r < 4; ++r) {
                    const int oc = oc0 + wm*32 + mi*16 + quad*4 + r;
                    size_t addr = ((((size_t)n*OCn + oc)*OSn + td*8 + ni)*OSn + th*4 + ohl)*OSn
                                  + tw*4 + owl;
                    out[addr] = vv[r];
                }
            }
        }
    }
}

// ============================================================
// Fallback (round-1 fused fp32 kernel) if ws too small
// ============================================================
#define TD 4
#define TH 4
#define TW 8
#define XD 13
#define XH 13
#define XW 21
#define YW 17
#define YD 9
#define YH 9
#define XS_LEN (XD*XH*XW)
#define AS_OFF XS_LEN
#define AS_LEN (XD*XH*YW)
#define BS_OFF (AS_OFF + AS_LEN)
#define BS_LEN (XD*YH*YW)
#define WS_OFF 8412
#define WROW 136
#define LDS_TOT (WS_OFF + 27*WROW)

__global__ __launch_bounds__(256) void conv_down3d_fused(
    const float* __restrict__ x, const float* __restrict__ w,
    const float* __restrict__ bias, float* __restrict__ out)
{
    __shared__ float lds[LDS_TOT];
    float* xs = lds;
    float* as = lds + AS_OFF;
    float* bs = lds + BS_OFF;
    float* ws = lds + WS_OFF;
    float* ys = lds;

    const int tid = threadIdx.x;
    int s = blockIdx.x;
    const int tw = s % 3; s /= 3;
    const int th = s % 6; const int td = s / 6;
    const int od0 = td*TD, oh0 = th*TH, ow0 = tw*TW;
    const int oc0 = blockIdx.y * 128;
    const int n   = blockIdx.z;
    const int og = tid >> 4;
    const int pg = tid & 15;
    const int od = pg >> 2;
    const int oh = pg & 3;

    float acc[8][8];
    #pragma unroll
    for (int o = 0; o < 8; ++o) {
        const float bv = bias[oc0 + og*8 + o];
        #pragma unroll
        for (int p = 0; p < 8; ++p) acc[o][p] = bv;
    }

    const int x0d = 2*od0 - 3, x0h = 2*oh0 - 3, x0w = 2*ow0 - 3;
    const float* xn = x + (size_t)n * ICn * (ISn*ISn*ISn);
    const float* wg = w + (size_t)oc0 * (ICn*27);

    for (int ic = 0; ic < ICn; ++ic) {
        const float* xin = xn + (size_t)ic * (ISn*ISn*ISn);
        for (int idx = tid; idx < XS_LEN; idx += 256) {
            int lz = idx / (XH*XW);
            int r  = idx - lz*(XH*XW);
            int ly = r / XW;
            int lx = r - ly*XW;
            int gz = x0d + lz, gy = x0h + ly, gx = x0w + lx;
            float v = 0.0f;
            if ((unsigned)gz < (unsigned)ISn && (unsigned)gy < (unsigned)ISn &&
                (unsigned)gx < (unsigned)ISn)
                v = xin[((size_t)gz*ISn + gy)*ISn + gx];
            xs[idx] = v;
        }
        for (int idx = tid; idx < 27*128; idx += 256) {
            int oc  = idx / 27;
            int tap = idx - oc*27;
            ws[tap*WROW + oc] = wg[(size_t)oc*(ICn*27) + ic*27 + tap];
        }
        __syncthreads();
        for (int idx = tid; idx < AS_LEN; idx += 256) {
            int z = idx / (XH*YW);
            int r = idx - z*(XH*YW);
            int yy = r / YW;
            int u  = r - yy*YW;
            const float* p0 = &xs[(z*XH + yy)*XW + u];
            as[idx] = K0f*(p0[0] + p0[4]) + K1f*(p0[1] + p0[2] + p0[3]);
        }
        __syncthreads();
        for (int idx = tid; idx < BS_LEN; idx += 256) {
            int z = idx / (YH*YW);
            int r = idx - z*(YH*YW);
            int v = r / YW;
            int u = r - v*YW;
            const float* p0 = &as[(z*XH + v)*YW + u];
            bs[idx] = K0f*(p0[0] + p0[4*YW]) + K1f*(p0[YW] + p0[2*YW] + p0[3*YW]);
        }
        __syncthreads();
        for (int idx = tid; idx < YD*YH*YW; idx += 256) {
            int t = idx / (YH*YW);
            int r = idx - t*(YH*YW);
            int v = r / YW;
            int u = r - v*YW;
            const float* p0 = &bs[(t*YH + v)*YW + u];
            ys[idx] = K0f*(p0[0] + p0[4*(YH*YW)]) +
                      K1f*(p0[YH*YW] + p0[2*(YH*YW)] + p0[3*(YH*YW)]);
        }
        __syncthreads();
        #pragma unroll
        for (int a = 0; a < 3; ++a) {
            #pragma unroll
            for (int b = 0; b < 3; ++b) {
                const float* yrow = &ys[((2*od + a)*YH + (2*oh + b))*YW];
                #pragma unroll
                for (int c = 0; c < 3; ++c) {
                    float yv[8];
                    #pragma unroll
                    for (int p = 0; p < 8; ++p) yv[p] = yrow[2*p + c];
                    const float* wrow = &ws[(a*9 + b*3 + c)*WROW + og*8];
                    float wv[8];
                    #pragma unroll
                    for (int o = 0; o < 8; ++o) wv[o] = wrow[o];
                    #pragma unroll
                    for (int o = 0; o < 8; ++o)
                        #pragma unroll
                        for (int p = 0; p < 8; ++p)
                            acc[o][p] += wv[o] * yv[p];
                }
            }
        }
        __syncthreads();
    }
    #pragma unroll
    for (int o = 0; o < 8; ++o) {
        size_t base = ((((size_t)n*OCn + oc0 + og*8 + o)*OSn + (od0+od))*OSn + (oh0+oh))*OSn + ow0;
        float4 v0 = make_float4(acc[o][0], acc[o][1], acc[o][2], acc[o][3]);
        float4 v1 = make_float4(acc[o][4], acc[o][5], acc[o][6], acc[o][7]);
        *(float4*)(out + base)     = v0;
        *(float4*)(out + base + 4) = v1;
    }
}

// ============================================================
extern "C" void kernel_launch(void* const* d_in, const int* in_sizes, int n_in,
                              void* d_out, int out_size, void* d_ws, size_t ws_size,
                              hipStream_t stream) {
    const float* x    = (const float*)d_in[0];
    const float* w    = (const float*)d_in[1];
    const float* bias = (const float*)d_in[2];
    float* out        = (float*)d_out;

    const size_t Y_OFF    = 2097152;                      // 2 MB aligned
    const size_t Y_BYTES  = (size_t)2 * 16 * YV * 8 * 2;  // 60.2 MB
    const size_t WS_NEED  = Y_OFF + Y_BYTES;

    if (ws_size < WS_NEED) {
        dim3 grid(6*6*3, OCn/128, 2);
        hipLaunchKernelGGL(conv_down3d_fused, grid, dim3(256), 0, stream, x, w, bias, out);
        return;
    }

    unsigned short* wt = (unsigned short*)d_ws;
    unsigned short* yb = (unsigned short*)((char*)d_ws + Y_OFF);

    hipLaunchKernelGGL(w_pack,     dim3(256),        dim3(256), 0, stream, w, wt);
    hipLaunchKernelGGL(fir_y_bf16, dim3(49, 32, 2),  dim3(256), 0, stream, x, yb);
    hipLaunchKernelGGL(conv_mfma,  dim3(216, 1, 2),  dim3(512), 0, stream, wt, yb, bias, out);
}

// Round 8
// 284.977 us; speedup vs baseline: 1.4506x; 1.0386x over previous
//
#include <hip/hip_runtime.h>

// ---------------- problem constants ----------------
#define ICn 128
#define OCn 256
#define ISn 48      // x spatial
#define OSn 24      // out spatial
#define YV  117649  // 49^3
#define K0f (1.0f/11.0f)
#define K1f (3.0f/11.0f)

typedef short  short8  __attribute__((ext_vector_type(8)));
typedef float  floatx4 __attribute__((ext_vector_type(4)));

static __device__ __forceinline__ unsigned short f2bf(float f) {
    union { float f; unsigned u; } v; v.f = f;
    unsigned r = (v.u + 0x7FFF + ((v.u >> 16) & 1)) >> 16;   // RNE
    return (unsigned short)r;
}

// async 16B global -> LDS (dest = wave-uniform base + lane*16)
static __device__ __forceinline__ void async_copy16(
    unsigned short* lds_base, const unsigned short* gsrc) {
    __builtin_amdgcn_global_load_lds(
        (const __attribute__((address_space(1))) void*)gsrc,
        (__attribute__((address_space(3))) void*)lds_base, 16, 0, 0);
}

// ============================================================
// Kernel 0: repack w (fp32, [256][128][3][3][3]) -> bf16 wt
// wt layout: [g=2][tap=27][ch=4][oc=128][ic=32]
// 256 blocks (one oc each).
// ============================================================
__global__ __launch_bounds__(256) void w_pack(
    const float* __restrict__ w, unsigned short* __restrict__ wt)
{
    __shared__ unsigned short lw[3456];   // [ch*32+ic][27] bf16, one oc
    const int tid = threadIdx.x;
    const int oc = blockIdx.x;            // 0..255
    const float* src = w + (size_t)oc * 3456;
    for (int i4 = tid; i4 < 864; i4 += 256) {
        floatx4 v = *(const floatx4*)(src + (size_t)i4*4);
        ushort4 u;
        u.x = f2bf(v.x); u.y = f2bf(v.y); u.z = f2bf(v.z); u.w = f2bf(v.w);
        *(ushort4*)(&lw[i4*4]) = u;
    }
    __syncthreads();
    const int g = oc >> 7, ol = oc & 127;
    for (int idx = tid; idx < 3456; idx += 256) {
        int i  = idx & 31;
        int ch = (idx >> 5) & 3;
        int t  = idx >> 7;
        wt[(((size_t)(g*27 + t)*4 + ch)*128 + ol)*32 + i] = lw[(ch*32 + i)*27 + t];
    }
}

// ============================================================
// Kernel 1: separable FIR  x(2,128,48^3) fp32 -> y bf16
// y layout: yb[n][icq8=16][sp=49^3][8ic]  (16-B groups)
// NEW this round: 8 ics per block (grid 49x16x2), outputs kept in
// REGISTERS across the ic loop (ov[2][7][4], 2 ics packed per uint,
// static indexing) and written as full 16B uint4 stores:
//  - kills the 2x HBM write amplification (117.9 -> ~60 MB): previously
//    two blocks each wrote 8B halves of every 16B group
//  - deletes ysl (19 KB), its per-ic ds_writes, and the whole flush
//    phase (its LDS reads were the main bank-conflict source)
// Staging/prefetch (T14) and filter math unchanged.
// ============================================================
__global__ __launch_bounds__(256, 3) void fir_y_bf16(
    const float* __restrict__ x, unsigned short* __restrict__ yb)
{
    __shared__ float xs[121*48];             // 23232 B  [(d*11+y)][48]

    const int tid  = threadIdx.x;
    const int wave = tid >> 6, lane = tid & 63;
    const int tz = blockIdx.x / 7, ty = blockIdx.x % 7;
    const int z0 = tz*7, y0 = ty*7;
    const int icg8 = blockIdx.y;             // 0..15 (8 ics each)
    const int n   = blockIdx.z;

    const size_t xbase = ((size_t)n*ICn + icg8*8) * (size_t)(ISn*ISn*ISn);

    floatx4 pf[6];
    int   cc[6], rowoff[6];
    bool  vld[6];
    #pragma unroll
    for (int s = 0; s < 6; ++s) {
        int idx = tid + 256*s;
        int r = idx / 12, c = idx - r*12;
        if (idx < 1452) {
            int d = r/11, yy = r - d*11;
            int gz = z0 - 3 + d, gy = y0 - 3 + yy;
            bool ok = ((unsigned)gz < 48u) && ((unsigned)gy < 48u);
            vld[s] = ok;
            rowoff[s] = r*48 + 4*c;
            cc[s] = ok ? ((gz*ISn + gy)*ISn + 4*c) : 0;
        } else { vld[s] = false; rowoff[s] = 0; cc[s] = 0; }
    }

    {
        const float* xin = x + xbase;
        #pragma unroll
        for (int s = 0; s < 6; ++s) {
            floatx4 v = {0.f,0.f,0.f,0.f};
            if (vld[s]) v = *(const floatx4*)(xin + cc[s]);
            pf[s] = v;
        }
    }

    // output registers: [k: zl=wave+4k][yl][ic-pair] (2 bf16 per uint)
    unsigned ov[2][7][4];

    #pragma unroll
    for (int ic = 0; ic < 8; ++ic) {
        // ---- write staged tile to LDS ----
        #pragma unroll
        for (int s = 0; s < 5; ++s)
            *(floatx4*)(xs + rowoff[s]) = pf[s];
        if (tid < 172) *(floatx4*)(xs + rowoff[5]) = pf[5];
        __syncthreads();                 // xs ready

        // ---- T14: issue prefetch for next ic AFTER the barrier ----
        if (ic < 7) {
            const float* xin = x + xbase + (size_t)(ic+1)*(ISn*ISn*ISn);
            #pragma unroll
            for (int s = 0; s < 6; ++s) {
                floatx4 v = {0.f,0.f,0.f,0.f};
                if (vld[s]) v = *(const floatx4*)(xin + cc[s]);
                pf[s] = v;
            }
        }

        // ---- compute: z-filter to g[11], y-filter in regs, x via shfl ----
        const int xp = lane;
        #pragma unroll
        for (int k = 0; k < 2; ++k) {
            const int zl = wave + 4*k;
            if (zl < 7) {
                float g[11];
                if (xp < 48) {
                    const float* col = xs + zl*528 + xp;
                    #pragma unroll
                    for (int Y = 0; Y < 11; ++Y) {
                        const float* q = col + Y*48;
                        g[Y] = K0f*(q[0] + q[4*528]) + K1f*(q[528] + q[2*528] + q[3*528]);
                    }
                } else {
                    #pragma unroll
                    for (int Y = 0; Y < 11; ++Y) g[Y] = 0.f;
                }
                #pragma unroll
                for (int yl = 0; yl < 7; ++yl) {
                    float h = K0f*(g[yl] + g[yl+4]) + K1f*(g[yl+1] + g[yl+2] + g[yl+3]);
                    float hm3 = __shfl(h, (lane + 61) & 63);
                    float hm2 = __shfl(h, (lane + 62) & 63);
                    float hm1 = __shfl(h, (lane + 63) & 63);
                    float hp1 = __shfl(h, (lane + 1) & 63);
                    float acc = K0f*(hm3 + hp1) + K1f*(hm2 + hm1 + h);
                    unsigned b = (unsigned)f2bf(acc);
                    if ((ic & 1) == 0) ov[k][yl][ic >> 1] = b;
                    else               ov[k][yl][ic >> 1] |= (b << 16);
                }
            }
        }
        __syncthreads();                 // compute done; prefetch drains here
    }

    // ---- epilogue: full 16B stores (8 ics per point), coalesced ----
    if (lane < 49) {
        unsigned short* yp = yb + ((size_t)(n*16 + icg8)) * YV * 8;
        #pragma unroll
        for (int k = 0; k < 2; ++k) {
            const int zl = wave + 4*k;
            if (zl < 7) {
                #pragma unroll
                for (int yl = 0; yl < 7; ++yl) {
                    size_t g_sp = (size_t)(z0+zl)*2401 + (size_t)(y0+yl)*49 + lane;
                    *(uint4*)(yp + g_sp*8) = make_uint4(
                        ov[k][yl][0], ov[k][yl][1], ov[k][yl][2], ov[k][yl][3]);
                }
            }
        }
    }
}

// ============================================================
// per-wave tap-range compute: 2 mi (32 oc) x 8 ni (od 0..7), taps [T0,T1)
// 8 MFMAs per A-load. A prefetched 2 taps ahead, 3 rot buffers.
// ============================================================
#define SLABZ 17
#define SLABSP (SLABZ*81)      // 1377
template<int T0, int T1>
static __device__ __forceinline__ void do_taps(
    const short8* __restrict__ wt8, int A0,
    const unsigned short* __restrict__ ys3,
    int quad, int oh2, int ow2,
    floatx4 (&acc)[2][8])
{
    short8 Ab[3][2];
    #pragma unroll
    for (int mi = 0; mi < 2; ++mi) Ab[0][mi] = wt8[A0 + T0*2048 + mi*64];
    #pragma unroll
    for (int mi = 0; mi < 2; ++mi) Ab[1][mi] = wt8[A0 + (T0+1)*2048 + mi*64];
    #pragma unroll
    for (int t = T0; t < T1; ++t) {
        const int k = t - T0;
        if (t + 2 < T1) {
            #pragma unroll
            for (int mi = 0; mi < 2; ++mi)
                Ab[(k+2)%3][mi] = wt8[A0 + (t+2)*2048 + mi*64];
        }
        const int a  = t / 9;
        const int b2 = (t / 3) % 3;
        const int c  = t % 3;
        #pragma unroll
        for (int nh = 0; nh < 2; ++nh) {           // B regs: 4 at a time
            short8 B[4];
            #pragma unroll
            for (int nj = 0; nj < 4; ++nj) {
                const int ni = nh*4 + nj;
                const int zs = 2*ni + a;           // od = ni, 0..16
                const int sp = zs*81 + (oh2 + b2)*9 + ow2 + c;
                B[nj] = *(const short8*)(&ys3[((size_t)quad*SLABSP + sp)*8]);
            }
            #pragma unroll
            for (int mi = 0; mi < 2; ++mi)
                #pragma unroll
                for (int nj = 0; nj < 4; ++nj)
                    acc[mi][nh*4+nj] = __builtin_amdgcn_mfma_f32_16x16x32_bf16(
                        Ab[k%3][mi], B[nj], acc[mi][nh*4+nj], 0, 0, 0);
        }
    }
}

// ============================================================
// Kernel 2: conv via MFMA.  out(2,256,24^3) fp32
// block = 128 oc x 128 pts (4x4x8-z out tile), 8 waves
// = 4(oc quarter wm) x 2(tap half wq).  (unchanged this round)
// ============================================================
__global__ __launch_bounds__(512, 2) void conv_mfma(
    const unsigned short* __restrict__ wt,
    const unsigned short* __restrict__ yb,
    const float* __restrict__ bias,
    float* __restrict__ out)
{
    __shared__ unsigned short ys3[4*SLABSP*8];   // 88128 B, entry idx at byte idx*16

    const int tid  = threadIdx.x;
    const int wav  = tid >> 6;      // 0..7
    const int lane = tid & 63;
    const int quad = lane >> 4;
    const int m    = lane & 15;
    const int wm   = wav & 3;       // oc quarter 0..3
    const int wq   = wav >> 2;      // tap half 0..1

    // ---- XCD-paired remap: g=0/1 of one spatial tile adjacent on one XCD ----
    const int bx0 = blockIdx.x;            // 0..215
    const int xcd = bx0 & 7;
    const int u   = bx0 >> 3;              // 0..26
    const int v   = xcd*27 + u;            // 0..215 bijective
    const int g    = v & 1;                // ocg
    const int sidx = v >> 1;               // spatial tile 0..107
    const int n    = blockIdx.z;

    const int td = sidx / 36; int r0 = sidx - td*36;   // td 0..2 (od tile of 8)
    const int th = r0 / 6;  const int tw = r0 - th*6;
    const int oc0 = g * 128;

    const int oh2 = (m >> 2) * 2;
    const int ow2 = (m & 3) * 2;

    floatx4 acc[2][8];
    #pragma unroll
    for (int mi = 0; mi < 2; ++mi) {
        floatx4 bv = {0.f, 0.f, 0.f, 0.f};
        if (wq == 0)
            bv = *(const floatx4*)(bias + oc0 + wm*32 + mi*16 + quad*4);
        #pragma unroll
        for (int ni = 0; ni < 8; ++ni) acc[mi][ni] = bv;
    }

    const short8* wt8 = (const short8*)wt;
    const int gz0 = 16*td, gy0 = 8*th, gx0 = 8*tw;

    // ---- per-lane global offsets for the 11 staging slots (once) ----
    const unsigned short* ybn = yb + (size_t)n * 16 * YV * 8;
    unsigned goff[11];
    #pragma unroll
    for (int s = 0; s < 11; ++s) {
        int idx = s*512 + tid;
        int i2 = (idx < 4*SLABSP) ? idx : 0;
        int icq = i2 / SLABSP, sp = i2 - icq*SLABSP;
        int zs = sp / 81; int r = sp - zs*81; int ysv = r / 9; int xsv = r - ysv*9;
        unsigned g_sp = (unsigned)(gz0 + zs)*2401u
                      + (unsigned)(gy0 + ysv)*49u + (unsigned)(gx0 + xsv);
        goff[s] = ((unsigned)icq*(unsigned)YV + g_sp) * 8u;   // ushort units
    }

    for (int chk = 0; chk < 4; ++chk) {
        if (chk) __syncthreads();          // prev compute done -> LDS free
        // ---- issue 11 async 16B copies: global -> LDS (no VGPR staging) ----
        {
            const unsigned short* src = ybn + (size_t)chk * 4u * (size_t)YV * 8u;
            #pragma unroll
            for (int s = 0; s < 11; ++s) {
                if (s < 10 || tid < 388)   // entries 5508.. absent
                    async_copy16(ys3 + ((size_t)(s*512 + wav*64))*8u, src + goff[s]);
            }
        }
        __syncthreads();                    // vmcnt(0) drain: LDS ready

        const int A0 = (g*108 + chk)*512 + (wm*32 + m)*4 + quad;  // short8 units
        if (wq == 0)
            do_taps< 0, 14>(wt8, A0, ys3, quad, oh2, ow2, acc);
        else
            do_taps<14, 27>(wt8, A0, ys3, quad, oh2, ow2, acc);
    }

    // ---- reduce wq1 -> wq0 through LDS (ys3 dead; 64 KB used) ----
    __syncthreads();
    float* red = (float*)ys3;
    if (wq == 1) {
        #pragma unroll
        for (int mi = 0; mi < 2; ++mi)
            #pragma unroll
            for (int ni = 0; ni < 8; ++ni)
                *(floatx4*)(red + (((wm*2 + mi)*8 + ni)*64 + lane)*4) = acc[mi][ni];
    }
    __syncthreads();
    if (wq == 0) {
        const int ohl = m >> 2, owl = m & 3;
        #pragma unroll
        for (int mi = 0; mi < 2; ++mi) {
            #pragma unroll
            for (int ni = 0; ni < 8; ++ni) {
                floatx4 vv = acc[mi][ni]
                    + *(const floatx4*)(red + (((wm*2 + mi)*8 + ni)*64 + lane)*4);
                #pragma unroll
                for (int r = 0; r < 4; ++r) {
                    const int oc = oc0 + wm*32 + mi*16 + quad*4 + r;
                    size_t addr = ((((size_t)n*OCn + oc)*OSn + td*8 + ni)*OSn + th*4 + ohl)*OSn
                                  + tw*4 + owl;
                    out[addr] = vv[r];
                }
            }
        }
    }
}

// ============================================================
// Fallback (round-1 fused fp32 kernel) if ws too small
// ============================================================
#define TD 4
#define TH 4
#define TW 8
#define XD 13
#define XH 13
#define XW 21
#define YW 17
#define YD 9
#define YH 9
#define XS_LEN (XD*XH*XW)
#define AS_OFF XS_LEN
#define AS_LEN (XD*XH*YW)
#define BS_OFF (AS_OFF + AS_LEN)
#define BS_LEN (XD*YH*YW)
#define WS_OFF 8412
#define WROW 136
#define LDS_TOT (WS_OFF + 27*WROW)

__global__ __launch_bounds__(256) void conv_down3d_fused(
    const float* __restrict__ x, const float* __restrict__ w,
    const float* __restrict__ bias, float* __restrict__ out)
{
    __shared__ float lds[LDS_TOT];
    float* xs = lds;
    float* as = lds + AS_OFF;
    float* bs = lds + BS_OFF;
    float* ws = lds + WS_OFF;
    float* ys = lds;

    const int tid = threadIdx.x;
    int s = blockIdx.x;
    const int tw = s % 3; s /= 3;
    const int th = s % 6; const int td = s / 6;
    const int od0 = td*TD, oh0 = th*TH, ow0 = tw*TW;
    const int oc0 = blockIdx.y * 128;
    const int n   = blockIdx.z;
    const int og = tid >> 4;
    const int pg = tid & 15;
    const int od = pg >> 2;
    const int oh = pg & 3;

    float acc[8][8];
    #pragma unroll
    for (int o = 0; o < 8; ++o) {
        const float bv = bias[oc0 + og*8 + o];
        #pragma unroll
        for (int p = 0; p < 8; ++p) acc[o][p] = bv;
    }

    const int x0d = 2*od0 - 3, x0h = 2*oh0 - 3, x0w = 2*ow0 - 3;
    const float* xn = x + (size_t)n * ICn * (ISn*ISn*ISn);
    const float* wg = w + (size_t)oc0 * (ICn*27);

    for (int ic = 0; ic < ICn; ++ic) {
        const float* xin = xn + (size_t)ic * (ISn*ISn*ISn);
        for (int idx = tid; idx < XS_LEN; idx += 256) {
            int lz = idx / (XH*XW);
            int r  = idx - lz*(XH*XW);
            int ly = r / XW;
            int lx = r - ly*XW;
            int gz = x0d + lz, gy = x0h + ly, gx = x0w + lx;
            float v = 0.0f;
            if ((unsigned)gz < (unsigned)ISn && (unsigned)gy < (unsigned)ISn &&
                (unsigned)gx < (unsigned)ISn)
                v = xin[((size_t)gz*ISn + gy)*ISn + gx];
            xs[idx] = v;
        }
        for (int idx = tid; idx < 27*128; idx += 256) {
            int oc  = idx / 27;
            int tap = idx - oc*27;
            ws[tap*WROW + oc] = wg[(size_t)oc*(ICn*27) + ic*27 + tap];
        }
        __syncthreads();
        for (int idx = tid; idx < AS_LEN; idx += 256) {
            int z = idx / (XH*YW);
            int r = idx - z*(XH*YW);
            int yy = r / YW;
            int u  = r - yy*YW;
            const float* p0 = &xs[(z*XH + yy)*XW + u];
            as[idx] = K0f*(p0[0] + p0[4]) + K1f*(p0[1] + p0[2] + p0[3]);
        }
        __syncthreads();
        for (int idx = tid; idx < BS_LEN; idx += 256) {
            int z = idx / (YH*YW);
            int r = idx - z*(YH*YW);
            int v = r / YW;
            int u = r - v*YW;
            const float* p0 = &as[(z*XH + v)*YW + u];
            bs[idx] = K0f*(p0[0] + p0[4*YW]) + K1f*(p0[YW] + p0[2*YW] + p0[3*YW]);
        }
        __syncthreads();
        for (int idx = tid; idx < YD*YH*YW; idx += 256) {
            int t = idx / (YH*YW);
            int r = idx - t*(YH*YW);
            int v = r / YW;
            int u = r - v*YW;
            const float* p0 = &bs[(t*YH + v)*YW + u];
            ys[idx] = K0f*(p0[0] + p0[4*(YH*YW)]) +
                      K1f*(p0[YH*YW] + p0[2*(YH*YW)] + p0[3*(YH*YW)]);
        }
        __syncthreads();
        #pragma unroll
        for (int a = 0; a < 3; ++a) {
            #pragma unroll
            for (int b = 0; b < 3; ++b) {
                const float* yrow = &ys[((2*od + a)*YH + (2*oh + b))*YW];
                #pragma unroll
                for (int c = 0; c < 3; ++c) {
                    float yv[8];
                    #pragma unroll
                    for (int p = 0; p < 8; ++p) yv[p] = yrow[2*p + c];
                    const float* wrow = &ws[(a*9 + b*3 + c)*WROW + og*8];
                    float wv[8];
                    #pragma unroll
                    for (int o = 0; o < 8; ++o) wv[o] = wrow[o];
                    #pragma unroll
                    for (int o = 0; o < 8; ++o)
                        #pragma unroll
                        for (int p = 0; p < 8; ++p)
                            acc[o][p] += wv[o] * yv[p];
                }
            }
        }
        __syncthreads();
    }
    #pragma unroll
    for (int o = 0; o < 8; ++o) {
        size_t base = ((((size_t)n*OCn + oc0 + og*8 + o)*OSn + (od0+od))*OSn + (oh0+oh))*OSn + ow0;
        float4 v0 = make_float4(acc[o][0], acc[o][1], acc[o][2], acc[o][3]);
        float4 v1 = make_float4(acc[o][4], acc[o][5], acc[o][6], acc[o][7]);
        *(float4*)(out + base)     = v0;
        *(float4*)(out + base + 4) = v1;
    }
}

// ============================================================
extern "C" void kernel_launch(void* const* d_in, const int* in_sizes, int n_in,
                              void* d_out, int out_size, void* d_ws, size_t ws_size,
                              hipStream_t stream) {
    const float* x    = (const float*)d_in[0];
    const float* w    = (const float*)d_in[1];
    const float* bias = (const float*)d_in[2];
    float* out        = (float*)d_out;

    const size_t Y_OFF    = 2097152;                      // 2 MB aligned
    const size_t Y_BYTES  = (size_t)2 * 16 * YV * 8 * 2;  // 60.2 MB
    const size_t WS_NEED  = Y_OFF + Y_BYTES;

    if (ws_size < WS_NEED) {
        dim3 grid(6*6*3, OCn/128, 2);
        hipLaunchKernelGGL(conv_down3d_fused, grid, dim3(256), 0, stream, x, w, bias, out);
        return;
    }

    unsigned short* wt = (unsigned short*)d_ws;
    unsigned short* yb = (unsigned short*)((char*)d_ws + Y_OFF);

    hipLaunchKernelGGL(w_pack,     dim3(256),        dim3(256), 0, stream, w, wt);
    hipLaunchKernelGGL(fir_y_bf16, dim3(49, 16, 2),  dim3(256), 0, stream, x, yb);
    hipLaunchKernelGGL(conv_mfma,  dim3(216, 1, 2),  dim3(512), 0, stream, wt, yb, bias, out);
}

// Round 10
// 277.348 us; speedup vs baseline: 1.4905x; 1.0275x over previous
//
#include <hip/hip_runtime.h>

// ---------------- problem constants ----------------
#define ICn 128
#define OCn 256
#define ISn 48      // x spatial
#define OSn 24      // out spatial
#define YV  117649  // 49^3
#define K0f (1.0f/11.0f)
#define K1f (3.0f/11.0f)

typedef short  short8  __attribute__((ext_vector_type(8)));
typedef float  floatx4 __attribute__((ext_vector_type(4)));

static __device__ __forceinline__ unsigned short f2bf(float f) {
    union { float f; unsigned u; } v; v.f = f;
    unsigned r = (v.u + 0x7FFF + ((v.u >> 16) & 1)) >> 16;   // RNE
    return (unsigned short)r;
}

// async 16B global -> LDS (dest = wave-uniform base + lane*16)
static __device__ __forceinline__ void async_copy16(
    unsigned short* lds_base, const unsigned short* gsrc) {
    __builtin_amdgcn_global_load_lds(
        (const __attribute__((address_space(1))) void*)gsrc,
        (__attribute__((address_space(3))) void*)lds_base, 16, 0, 0);
}

// ============================================================
// Kernel 0: repack w (fp32, [256][128][3][3][3]) -> bf16 wt
// wt layout: [g=2][tap=27][ch=4][oc=128][ic=32]
// 256 blocks (one oc each).
// ============================================================
__global__ __launch_bounds__(256) void w_pack(
    const float* __restrict__ w, unsigned short* __restrict__ wt)
{
    __shared__ unsigned short lw[3456];   // [ch*32+ic][27] bf16, one oc
    const int tid = threadIdx.x;
    const int oc = blockIdx.x;            // 0..255
    const float* src = w + (size_t)oc * 3456;
    for (int i4 = tid; i4 < 864; i4 += 256) {
        floatx4 v = *(const floatx4*)(src + (size_t)i4*4);
        ushort4 u;
        u.x = f2bf(v.x); u.y = f2bf(v.y); u.z = f2bf(v.z); u.w = f2bf(v.w);
        *(ushort4*)(&lw[i4*4]) = u;
    }
    __syncthreads();
    const int g = oc >> 7, ol = oc & 127;
    for (int idx = tid; idx < 3456; idx += 256) {
        int i  = idx & 31;
        int ch = (idx >> 5) & 3;
        int t  = idx >> 7;
        wt[(((size_t)(g*27 + t)*4 + ch)*128 + ol)*32 + i] = lw[(ch*32 + i)*27 + t];
    }
}

// ============================================================
// Kernel 1: separable FIR  x(2,128,48^3) fp32 -> y bf16
// y layout: yb[n][icq8=16][sp=49^3][8ic]  (16-B groups)
// Round-9 structure with the FIX: phase-1 slot sweep now covers all
// 528 slots (was tid+256*{0,1} = 512 -> zfl rows Y=10, xp>=32 were
// uninitialized garbage, absmax 3.2e4).
//  - phase-1 sliding-window z-filter: threads own (Y,xp) slots, read
//    the 11-deep d-column ONCE (conflict-free), produce all 7 zl
//    outputs -> zfl (14.8 KB). Kills the 3.2x re-read of xs.
//  - 3-shuffle x-filter: a=h+shfl(h,+1); b=shfl(a,-2); hm3=shfl(h,-3);
//    out = K0*(hm3+(a-h)) + K1*(b+h)
// ds-insts/wave/ic: 172 -> ~106. Barriers 2/ic. LDS 38.0 KB.
// ============================================================
__global__ __launch_bounds__(256, 3) void fir_y_bf16(
    const float* __restrict__ x, unsigned short* __restrict__ yb)
{
    __shared__ float xs[121*48];             // 23232 B  [(d*11+y)][48]
    __shared__ float zfl[7*11*48];           // 14784 B  [zl][Y][48]

    const int tid  = threadIdx.x;
    const int wave = tid >> 6, lane = tid & 63;
    const int tz = blockIdx.x / 7, ty = blockIdx.x % 7;
    const int z0 = tz*7, y0 = ty*7;
    const int icg8 = blockIdx.y;             // 0..15 (8 ics each)
    const int n   = blockIdx.z;

    const size_t xbase = ((size_t)n*ICn + icg8*8) * (size_t)(ISn*ISn*ISn);

    floatx4 pf[6];
    int   cc[6], rowoff[6];
    bool  vld[6];
    #pragma unroll
    for (int s = 0; s < 6; ++s) {
        int idx = tid + 256*s;
        int r = idx / 12, c = idx - r*12;
        if (idx < 1452) {
            int d = r/11, yy = r - d*11;
            int gz = z0 - 3 + d, gy = y0 - 3 + yy;
            bool ok = ((unsigned)gz < 48u) && ((unsigned)gy < 48u);
            vld[s] = ok;
            rowoff[s] = r*48 + 4*c;
            cc[s] = ok ? ((gz*ISn + gy)*ISn + 4*c) : 0;
        } else { vld[s] = false; rowoff[s] = 0; cc[s] = 0; }
    }

    {
        const float* xin = x + xbase;
        #pragma unroll
        for (int s = 0; s < 6; ++s) {
            floatx4 v = {0.f,0.f,0.f,0.f};
            if (vld[s]) v = *(const floatx4*)(xin + cc[s]);
            pf[s] = v;
        }
    }

    // output registers: [k: zl=wave+4k][yl][ic-pair] (2 bf16 per uint)
    unsigned ov[2][7][4];

    #pragma unroll
    for (int ic = 0; ic < 8; ++ic) {
        // ---- stage: write tile to xs ----
        #pragma unroll
        for (int s = 0; s < 5; ++s)
            *(floatx4*)(xs + rowoff[s]) = pf[s];
        if (tid < 172) *(floatx4*)(xs + rowoff[5]) = pf[5];
        __syncthreads();                 // bar1: xs ready

        // ---- phase 1: sliding-window z-filter -> zfl (ALL 528 slots) ----
        #pragma unroll
        for (int slot = tid; slot < 528; slot += 256) {
            float v[11];
            const float* col = xs + slot;        // slot = Y*48 + xp
            #pragma unroll
            for (int d = 0; d < 11; ++d) v[d] = col[d*528];
            #pragma unroll
            for (int zl = 0; zl < 7; ++zl) {
                zfl[zl*528 + slot] =
                    K0f*(v[zl] + v[zl+4]) + K1f*(v[zl+1] + v[zl+2] + v[zl+3]);
            }
        }
        __syncthreads();                 // bar2: zfl ready

        // ---- T14: issue prefetch for next ic (drains at next bar1) ----
        if (ic < 7) {
            const float* xin = x + xbase + (size_t)(ic+1)*(ISn*ISn*ISn);
            #pragma unroll
            for (int s = 0; s < 6; ++s) {
                floatx4 v = {0.f,0.f,0.f,0.f};
                if (vld[s]) v = *(const floatx4*)(xin + cc[s]);
                pf[s] = v;
            }
        }

        // ---- phase 2: y-filter in regs, x via 3 shuffles ----
        const int xp = lane;
        #pragma unroll
        for (int k = 0; k < 2; ++k) {
            const int zl = wave + 4*k;
            if (zl < 7) {
                float g[11];
                if (xp < 48) {
                    const float* q = zfl + zl*528 + xp;
                    #pragma unroll
                    for (int Y = 0; Y < 11; ++Y) g[Y] = q[Y*48];
                } else {
                    #pragma unroll
                    for (int Y = 0; Y < 11; ++Y) g[Y] = 0.f;
                }
                #pragma unroll
                for (int yl = 0; yl < 7; ++yl) {
                    float h = K0f*(g[yl] + g[yl+4]) + K1f*(g[yl+1] + g[yl+2] + g[yl+3]);
                    float a   = h + __shfl(h, (lane + 1) & 63);    // h[u]+h[u+1]
                    float hm3 = __shfl(h, (lane + 61) & 63);       // h[u-3]
                    float b   = __shfl(a, (lane + 62) & 63);       // h[u-2]+h[u-1]
                    float acc = K0f*(hm3 + (a - h)) + K1f*(b + h);
                    unsigned bb = (unsigned)f2bf(acc);
                    if ((ic & 1) == 0) ov[k][yl][ic >> 1] = bb;
                    else               ov[k][yl][ic >> 1] |= (bb << 16);
                }
            }
        }
        // no barrier here: next stage writes xs (phase2 reads only zfl);
        // zfl(ic+1) writes are fenced from phase2(ic) readers by bar1.
    }

    // ---- epilogue: full 16B stores (8 ics per point), coalesced ----
    if (lane < 49) {
        unsigned short* yp = yb + ((size_t)(n*16 + icg8)) * YV * 8;
        #pragma unroll
        for (int k = 0; k < 2; ++k) {
            const int zl = wave + 4*k;
            if (zl < 7) {
                #pragma unroll
                for (int yl = 0; yl < 7; ++yl) {
                    size_t g_sp = (size_t)(z0+zl)*2401 + (size_t)(y0+yl)*49 + lane;
                    *(uint4*)(yp + g_sp*8) = make_uint4(
                        ov[k][yl][0], ov[k][yl][1], ov[k][yl][2], ov[k][yl][3]);
                }
            }
        }
    }
}

// ============================================================
// per-wave tap-range compute: 2 mi (32 oc) x 8 ni (od 0..7), taps [T0,T1)
// 8 MFMAs per A-load. A prefetched 2 taps ahead, 3 rot buffers.
// ============================================================
#define SLABZ 17
#define SLABSP (SLABZ*81)      // 1377
template<int T0, int T1>
static __device__ __forceinline__ void do_taps(
    const short8* __restrict__ wt8, int A0,
    const unsigned short* __restrict__ ys3,
    int quad, int oh2, int ow2,
    floatx4 (&acc)[2][8])
{
    short8 Ab[3][2];
    #pragma unroll
    for (int mi = 0; mi < 2; ++mi) Ab[0][mi] = wt8[A0 + T0*2048 + mi*64];
    #pragma unroll
    for (int mi = 0; mi < 2; ++mi) Ab[1][mi] = wt8[A0 + (T0+1)*2048 + mi*64];
    #pragma unroll
    for (int t = T0; t < T1; ++t) {
        const int k = t - T0;
        if (t + 2 < T1) {
            #pragma unroll
            for (int mi = 0; mi < 2; ++mi)
                Ab[(k+2)%3][mi] = wt8[A0 + (t+2)*2048 + mi*64];
        }
        const int a  = t / 9;
        const int b2 = (t / 3) % 3;
        const int c  = t % 3;
        #pragma unroll
        for (int nh = 0; nh < 2; ++nh) {           // B regs: 4 at a time
            short8 B[4];
            #pragma unroll
            for (int nj = 0; nj < 4; ++nj) {
                const int ni = nh*4 + nj;
                const int zs = 2*ni + a;           // od = ni, 0..16
                const int sp = zs*81 + (oh2 + b2)*9 + ow2 + c;
                B[nj] = *(const short8*)(&ys3[((size_t)quad*SLABSP + sp)*8]);
            }
            #pragma unroll
            for (int mi = 0; mi < 2; ++mi)
                #pragma unroll
                for (int nj = 0; nj < 4; ++nj)
                    acc[mi][nh*4+nj] = __builtin_amdgcn_mfma_f32_16x16x32_bf16(
                        Ab[k%3][mi], B[nj], acc[mi][nh*4+nj], 0, 0, 0);
        }
    }
}

// ============================================================
// Kernel 2: conv via MFMA.  out(2,256,24^3) fp32
// block = 128 oc x 128 pts (4x4x8-z out tile), 8 waves
// = 4(oc quarter wm) x 2(tap half wq).  (unchanged)
// ============================================================
__global__ __launch_bounds__(512, 2) void conv_mfma(
    const unsigned short* __restrict__ wt,
    const unsigned short* __restrict__ yb,
    const float* __restrict__ bias,
    float* __restrict__ out)
{
    __shared__ unsigned short ys3[4*SLABSP*8];   // 88128 B, entry idx at byte idx*16

    const int tid  = threadIdx.x;
    const int wav  = tid >> 6;      // 0..7
    const int lane = tid & 63;
    const int quad = lane >> 4;
    const int m    = lane & 15;
    const int wm   = wav & 3;       // oc quarter 0..3
    const int wq   = wav >> 2;      // tap half 0..1

    // ---- XCD-paired remap: g=0/1 of one spatial tile adjacent on one XCD ----
    const int bx0 = blockIdx.x;            // 0..215
    const int xcd = bx0 & 7;
    const int u   = bx0 >> 3;              // 0..26
    const int v   = xcd*27 + u;            // 0..215 bijective
    const int g    = v & 1;                // ocg
    const int sidx = v >> 1;               // spatial tile 0..107
    const int n    = blockIdx.z;

    const int td = sidx / 36; int r0 = sidx - td*36;   // td 0..2 (od tile of 8)
    const int th = r0 / 6;  const int tw = r0 - th*6;
    const int oc0 = g * 128;

    const int oh2 = (m >> 2) * 2;
    const int ow2 = (m & 3) * 2;

    floatx4 acc[2][8];
    #pragma unroll
    for (int mi = 0; mi < 2; ++mi) {
        floatx4 bv = {0.f, 0.f, 0.f, 0.f};
        if (wq == 0)
            bv = *(const floatx4*)(bias + oc0 + wm*32 + mi*16 + quad*4);
        #pragma unroll
        for (int ni = 0; ni < 8; ++ni) acc[mi][ni] = bv;
    }

    const short8* wt8 = (const short8*)wt;
    const int gz0 = 16*td, gy0 = 8*th, gx0 = 8*tw;

    // ---- per-lane global offsets for the 11 staging slots (once) ----
    const unsigned short* ybn = yb + (size_t)n * 16 * YV * 8;
    unsigned goff[11];
    #pragma unroll
    for (int s = 0; s < 11; ++s) {
        int idx = s*512 + tid;
        int i2 = (idx < 4*SLABSP) ? idx : 0;
        int icq = i2 / SLABSP, sp = i2 - icq*SLABSP;
        int zs = sp / 81; int r = sp - zs*81; int ysv = r / 9; int xsv = r - ysv*9;
        unsigned g_sp = (unsigned)(gz0 + zs)*2401u
                      + (unsigned)(gy0 + ysv)*49u + (unsigned)(gx0 + xsv);
        goff[s] = ((unsigned)icq*(unsigned)YV + g_sp) * 8u;   // ushort units
    }

    for (int chk = 0; chk < 4; ++chk) {
        if (chk) __syncthreads();          // prev compute done -> LDS free
        // ---- issue 11 async 16B copies: global -> LDS (no VGPR staging) ----
        {
            const unsigned short* src = ybn + (size_t)chk * 4u * (size_t)YV * 8u;
            #pragma unroll
            for (int s = 0; s < 11; ++s) {
                if (s < 10 || tid < 388)   // entries 5508.. absent
                    async_copy16(ys3 + ((size_t)(s*512 + wav*64))*8u, src + goff[s]);
            }
        }
        __syncthreads();                    // vmcnt(0) drain: LDS ready

        const int A0 = (g*108 + chk)*512 + (wm*32 + m)*4 + quad;  // short8 units
        if (wq == 0)
            do_taps< 0, 14>(wt8, A0, ys3, quad, oh2, ow2, acc);
        else
            do_taps<14, 27>(wt8, A0, ys3, quad, oh2, ow2, acc);
    }

    // ---- reduce wq1 -> wq0 through LDS (ys3 dead; 64 KB used) ----
    __syncthreads();
    float* red = (float*)ys3;
    if (wq == 1) {
        #pragma unroll
        for (int mi = 0; mi < 2; ++mi)
            #pragma unroll
            for (int ni = 0; ni < 8; ++ni)
                *(floatx4*)(red + (((wm*2 + mi)*8 + ni)*64 + lane)*4) = acc[mi][ni];
    }
    __syncthreads();
    if (wq == 0) {
        const int ohl = m >> 2, owl = m & 3;
        #pragma unroll
        for (int mi = 0; mi < 2; ++mi) {
            #pragma unroll
            for (int ni = 0; ni < 8; ++ni) {
                floatx4 vv = acc[mi][ni]
                    + *(const floatx4*)(red + (((wm*2 + mi)*8 + ni)*64 + lane)*4);
                #pragma unroll
                for (int r = 0; r < 4; ++r) {
                    const int oc = oc0 + wm*32 + mi*16 + quad*4 + r;
                    size_t addr = ((((size_t)n*OCn + oc)*OSn + td*8 + ni)*OSn + th*4 + ohl)*OSn
                                  + tw*4 + owl;
                    out[addr] = vv[r];
                }
            }
        }
    }
}

// ============================================================
// Fallback (round-1 fused fp32 kernel) if ws too small
// ============================================================
#define TD 4
#define TH 4
#define TW 8
#define XD 13
#define XH 13
#define XW 21
#define YW 17
#define YD 9
#define YH 9
#define XS_LEN (XD*XH*XW)
#define AS_OFF XS_LEN
#define AS_LEN (XD*XH*YW)
#define BS_OFF (AS_OFF + AS_LEN)
#define BS_LEN (XD*YH*YW)
#define WS_OFF 8412
#define WROW 136
#define LDS_TOT (WS_OFF + 27*WROW)

__global__ __launch_bounds__(256) void conv_down3d_fused(
    const float* __restrict__ x, const float* __restrict__ w,
    const float* __restrict__ bias, float* __restrict__ out)
{
    __shared__ float lds[LDS_TOT];
    float* xs = lds;
    float* as = lds + AS_OFF;
    float* bs = lds + BS_OFF;
    float* ws = lds + WS_OFF;
    float* ys = lds;

    const int tid = threadIdx.x;
    int s = blockIdx.x;
    const int tw = s % 3; s /= 3;
    const int th = s % 6; const int td = s / 6;
    const int od0 = td*TD, oh0 = th*TH, ow0 = tw*TW;
    const int oc0 = blockIdx.y * 128;
    const int n   = blockIdx.z;
    const int og = tid >> 4;
    const int pg = tid & 15;
    const int od = pg >> 2;
    const int oh = pg & 3;

    float acc[8][8];
    #pragma unroll
    for (int o = 0; o < 8; ++o) {
        const float bv = bias[oc0 + og*8 + o];
        #pragma unroll
        for (int p = 0; p < 8; ++p) acc[o][p] = bv;
    }

    const int x0d = 2*od0 - 3, x0h = 2*oh0 - 3, x0w = 2*ow0 - 3;
    const float* xn = x + (size_t)n * ICn * (ISn*ISn*ISn);
    const float* wg = w + (size_t)oc0 * (ICn*27);

    for (int ic = 0; ic < ICn; ++ic) {
        const float* xin = xn + (size_t)ic * (ISn*ISn*ISn);
        for (int idx = tid; idx < XS_LEN; idx += 256) {
            int lz = idx / (XH*XW);
            int r  = idx - lz*(XH*XW);
            int ly = r / XW;
            int lx = r - ly*XW;
            int gz = x0d + lz, gy = x0h + ly, gx = x0w + lx;
            float v = 0.0f;
            if ((unsigned)gz < (unsigned)ISn && (unsigned)gy < (unsigned)ISn &&
                (unsigned)gx < (unsigned)ISn)
                v = xin[((size_t)gz*ISn + gy)*ISn + gx];
            xs[idx] = v;
        }
        for (int idx = tid; idx < 27*128; idx += 256) {
            int oc  = idx / 27;
            int tap = idx - oc*27;
            ws[tap*WROW + oc] = wg[(size_t)oc*(ICn*27) + ic*27 + tap];
        }
        __syncthreads();
        for (int idx = tid; idx < AS_LEN; idx += 256) {
            int z = idx / (XH*YW);
            int r = idx - z*(XH*YW);
            int yy = r / YW;
            int u  = r - yy*YW;
            const float* p0 = &xs[(z*XH + yy)*XW + u];
            as[idx] = K0f*(p0[0] + p0[4]) + K1f*(p0[1] + p0[2] + p0[3]);
        }
        __syncthreads();
        for (int idx = tid; idx < BS_LEN; idx += 256) {
            int z = idx / (YH*YW);
            int r = idx - z*(YH*YW);
            int v = r / YW;
            int u = r - v*YW;
            const float* p0 = &as[(z*XH + v)*YW + u];
            bs[idx] = K0f*(p0[0] + p0[4*YW]) + K1f*(p0[YW] + p0[2*YW] + p0[3*YW]);
        }
        __syncthreads();
        for (int idx = tid; idx < YD*YH*YW; idx += 256) {
            int t = idx / (YH*YW);
            int r = idx - t*(YH*YW);
            int v = r / YW;
            int u = r - v*YW;
            const float* p0 = &bs[(t*YH + v)*YW + u];
            ys[idx] = K0f*(p0[0] + p0[4*(YH*YW)]) +
                      K1f*(p0[YH*YW] + p0[2*(YH*YW)] + p0[3*(YH*YW)]);
        }
        __syncthreads();
        #pragma unroll
        for (int a = 0; a < 3; ++a) {
            #pragma unroll
            for (int b = 0; b < 3; ++b) {
                const float* yrow = &ys[((2*od + a)*YH + (2*oh + b))*YW];
                #pragma unroll
                for (int c = 0; c < 3; ++c) {
                    float yv[8];
                    #pragma unroll
                    for (int p = 0; p < 8; ++p) yv[p] = yrow[2*p + c];
                    const float* wrow = &ws[(a*9 + b*3 + c)*WROW + og*8];
                    float wv[8];
                    #pragma unroll
                    for (int o = 0; o < 8; ++o) wv[o] = wrow[o];
                    #pragma unroll
                    for (int o = 0; o < 8; ++o)
                        #pragma unroll
                        for (int p = 0; p < 8; ++p)
                            acc[o][p] += wv[o] * yv[p];
                }
            }
        }
        __syncthreads();
    }
    #pragma unroll
    for (int o = 0; o < 8; ++o) {
        size_t base = ((((size_t)n*OCn + oc0 + og*8 + o)*OSn + (od0+od))*OSn + (oh0+oh))*OSn + ow0;
        float4 v0 = make_float4(acc[o][0], acc[o][1], acc[o][2], acc[o][3]);
        float4 v1 = make_float4(acc[o][4], acc[o][5], acc[o][6], acc[o][7]);
        *(float4*)(out + base)     = v0;
        *(float4*)(out + base + 4) = v1;
    }
}

// ============================================================
extern "C" void kernel_launch(void* const* d_in, const int* in_sizes, int n_in,
                              void* d_out, int out_size, void* d_ws, size_t ws_size,
                              hipStream_t stream) {
    const float* x    = (const float*)d_in[0];
    const float* w    = (const float*)d_in[1];
    const float* bias = (const float*)d_in[2];
    float* out        = (float*)d_out;

    const size_t Y_OFF    = 2097152;                      // 2 MB aligned
    const size_t Y_BYTES  = (size_t)2 * 16 * YV * 8 * 2;  // 60.2 MB
    const size_t WS_NEED  = Y_OFF + Y_BYTES;

    if (ws_size < WS_NEED) {
        dim3 grid(6*6*3, OCn/128, 2);
        hipLaunchKernelGGL(conv_down3d_fused, grid, dim3(256), 0, stream, x, w, bias, out);
        return;
    }

    unsigned short* wt = (unsigned short*)d_ws;
    unsigned short* yb = (unsigned short*)((char*)d_ws + Y_OFF);

    hipLaunchKernelGGL(w_pack,     dim3(256),        dim3(256), 0, stream, w, wt);
    hipLaunchKernelGGL(fir_y_bf16, dim3(49, 16, 2),  dim3(256), 0, stream, x, yb);
    hipLaunchKernelGGL(conv_mfma,  dim3(216, 1, 2),  dim3(512), 0, stream, wt, yb, bias, out);
}